// Round 2
// baseline (1470.203 us; speedup 1.0000x reference)
//
#include <hip/hip_runtime.h>
#include <hip/hip_bf16.h>
#include <type_traits>

// GLA attention forward: B=4,T=2048,D=2048,H=16,DK=64,DV=128,LR=16
// Inputs/outputs are float32 (per reference). bf16 used internally for MFMA.

using bf16x8 = __attribute__((ext_vector_type(8))) short;
using f32x4  = __attribute__((ext_vector_type(4))) float;

static __device__ __forceinline__ float bf2f(ushort u) {
  union { unsigned int i; float f; } v;
  v.i = ((unsigned int)u) << 16;
  return v.f;
}
static __device__ __forceinline__ ushort f2bf(float f) {
  __hip_bfloat16 h = __float2bfloat16(f);
  return *reinterpret_cast<ushort*>(&h);
}
static __device__ __forceinline__ unsigned int pack2(float lo, float hi) {
  return (unsigned int)f2bf(lo) | ((unsigned int)f2bf(hi) << 16);
}
static __device__ __forceinline__ void unpack8(uint4 v, float* f) {
  f[0] = bf2f((ushort)(v.x & 0xffff)); f[1] = bf2f((ushort)(v.x >> 16));
  f[2] = bf2f((ushort)(v.y & 0xffff)); f[3] = bf2f((ushort)(v.y >> 16));
  f[4] = bf2f((ushort)(v.z & 0xffff)); f[5] = bf2f((ushort)(v.z >> 16));
  f[6] = bf2f((ushort)(v.w & 0xffff)); f[7] = bf2f((ushort)(v.w >> 16));
}

#define GLDS16(g, l) __builtin_amdgcn_global_load_lds( \
    (const __attribute__((address_space(1))) unsigned int*)(g), \
    (__attribute__((address_space(3))) unsigned int*)(l), 16, 0, 0)

// ---------------- f32 -> bf16 elementwise (8 elems/thread) ----------------
__global__ __launch_bounds__(256) void f32_to_bf16(
    const float* __restrict__ in, ushort* __restrict__ out, long n) {
  long i = ((long)blockIdx.x * 256 + threadIdx.x) * 8;
  if (i >= n) return;
  float4 a = *(const float4*)(in + i);
  float4 b = *(const float4*)(in + i + 4);
  uint4 o;
  o.x = pack2(a.x, a.y); o.y = pack2(a.z, a.w);
  o.z = pack2(b.x, b.y); o.w = pack2(b.z, b.w);
  *(uint4*)(out + i) = o;
}

// ---------------- transpose f32 in[R][C] -> bf16 out[C][R] ----------------
__global__ __launch_bounds__(256) void transpose_f32_bf16(
    const float* __restrict__ in, ushort* __restrict__ out, int R, int C) {
  __shared__ float tile[64][65];
  const int t = threadIdx.x;
  const int tc = blockIdx.x * 64;   // col tile
  const int tr = blockIdx.y * 64;   // row tile
  const int lr = t >> 2;            // 0..63 (row)
  const int lc = (t & 3) * 16;      // col start (16 f32 per thread)
  const float* ip = in + (long)(tr + lr) * C + tc + lc;
#pragma unroll
  for (int j = 0; j < 4; ++j)
    *(float4*)(&tile[lr][lc + j * 4]) = *(const float4*)(ip + j * 4);
  __syncthreads();
  const int c = t >> 2;             // output row = tc + c
  const int r0 = (t & 3) * 16;      // output cols = tr + r0 .. +15
  ushort tmp[16];
#pragma unroll
  for (int j = 0; j < 16; ++j) tmp[j] = f2bf(tile[r0 + j][c]);
  ushort* op = out + (long)(tc + c) * R + tr + r0;
  *(uint4*)(op)     = *(uint4*)(tmp);
  *(uint4*)(op + 8) = *(uint4*)(tmp + 8);
}

// ---------------- GEMM: C[M][N] = A[M][K] * BT[N][K]^T, A/BT bf16 ----------------
// m97 structure: 128x128 tile, BK=32, 4 waves (2x2), 4x4 16x16x32 frags/wave.
template <typename OT>
__global__ __launch_bounds__(256) void gemm_bt(
    const ushort* __restrict__ A, const ushort* __restrict__ BT,
    OT* __restrict__ C, int M, int N, int K) {
  __shared__ ushort sA[128 * 32];
  __shared__ ushort sB[128 * 32];
  const int t = threadIdx.x;
  const int brow = blockIdx.y * 128;
  const int bcol = blockIdx.x * 128;
  const int w = t >> 6, l = t & 63;
  const int wr = (w >> 1) * 64, wc = (w & 1) * 64;
  const int lr = l & 15;
  const int kq = (l >> 4) * 8;

  f32x4 acc[4][4];
#pragma unroll
  for (int m = 0; m < 4; ++m)
#pragma unroll
    for (int n = 0; n < 4; ++n) acc[m][n] = (f32x4){0.f, 0.f, 0.f, 0.f};

  const int r0 = t >> 2;          // 0..63
  const int kk0 = (t & 3) << 3;   // 0,8,16,24
  const ushort* Ag  = A  + (long)(brow + r0) * K + kk0;
  const ushort* Ag2 = A  + (long)(brow + 64 + r0) * K + kk0;
  const ushort* Bg  = BT + (long)(bcol + r0) * K + kk0;
  const ushort* Bg2 = BT + (long)(bcol + 64 + r0) * K + kk0;
  ushort* sAp  = sA + t * 8;
  ushort* sAp2 = sA + (256 + t) * 8;
  ushort* sBp  = sB + t * 8;
  ushort* sBp2 = sB + (256 + t) * 8;

  for (int k0 = 0; k0 < K; k0 += 32) {
    __syncthreads();
    GLDS16(Ag + k0, sAp);
    GLDS16(Ag2 + k0, sAp2);
    GLDS16(Bg + k0, sBp);
    GLDS16(Bg2 + k0, sBp2);
    __syncthreads();   // compiler emits s_waitcnt vmcnt(0) before s_barrier
    bf16x8 af[4], bfr[4];
#pragma unroll
    for (int m = 0; m < 4; ++m)
      af[m] = *(const bf16x8*)(sA + (wr + m * 16 + lr) * 32 + kq);
#pragma unroll
    for (int n = 0; n < 4; ++n)
      bfr[n] = *(const bf16x8*)(sB + (wc + n * 16 + lr) * 32 + kq);
#pragma unroll
    for (int m = 0; m < 4; ++m)
#pragma unroll
      for (int n = 0; n < 4; ++n)
        acc[m][n] = __builtin_amdgcn_mfma_f32_16x16x32_bf16(af[m], bfr[n], acc[m][n], 0, 0, 0);
  }

  const int rq = (l >> 4) * 4;    // C/D: col=lane&15, row=(lane>>4)*4+reg
#pragma unroll
  for (int m = 0; m < 4; ++m)
#pragma unroll
    for (int n = 0; n < 4; ++n) {
      long row = brow + wr + m * 16 + rq;
      long col = bcol + wc + n * 16 + lr;
      OT* cp = C + row * N + col;
#pragma unroll
      for (int r = 0; r < 4; ++r) {
        if constexpr (std::is_same_v<OT, ushort>) cp[(long)r * N] = f2bf(acc[m][n][r]);
        else                                      cp[(long)r * N] = acc[m][n][r];
      }
    }
}

// ---------------- gate path: eg[m][1024] = exp(logsigmoid((x@Wgk1)@Wgk2+b)/16) ----------------
__global__ __launch_bounds__(256) void gate_kernel(
    const float* __restrict__ x, const float* __restrict__ Wgk1,
    const float* __restrict__ Wgk2, const float* __restrict__ bgk2,
    float* __restrict__ eg) {
  const int m = blockIdx.x;
  const int t = threadIdx.x;
  __shared__ float sx[2048];
  __shared__ float red[256];
  __shared__ float z1[16];
  const float* xr = x + (long)m * 2048;
  *(float4*)(sx + t * 8)     = *(const float4*)(xr + t * 8);
  *(float4*)(sx + t * 8 + 4) = *(const float4*)(xr + t * 8 + 4);
  __syncthreads();
  const int j = t & 15, seg = t >> 4;
  float s = 0.f;
  for (int d = 0; d < 128; ++d)
    s += sx[seg * 128 + d] * Wgk1[(seg * 128 + d) * 16 + j];
  red[t] = s;
  __syncthreads();
  if (t < 16) {
    float z = 0.f;
    for (int sg = 0; sg < 16; ++sg) z += red[sg * 16 + t];
    z1[t] = z;
  }
  __syncthreads();
#pragma unroll
  for (int r = 0; r < 4; ++r) {
    int n = r * 256 + t;
    float a = bgk2[n];
#pragma unroll
    for (int l2 = 0; l2 < 16; ++l2) a += z1[l2] * Wgk2[l2 * 1024 + n];
    float ls = fminf(a, 0.f) - log1pf(__expf(-fabsf(a)));  // logsigmoid
    eg[(long)m * 1024 + n] = __expf(ls * 0.0625f);
  }
}

// ---------------- recurrent scan ----------------
// block = (b,h,dv-chunk of 32). thread: dvl = t>>3 (0..31), dkg = t&7 (8 dk each).
// S[8] in regs; o[b,t,h,dv] = sum_dk q*scale*S  (8-lane shfl reduce).
__global__ __launch_bounds__(256) void scan_kernel(
    const ushort* __restrict__ qkvg, const float* __restrict__ eg,
    float* __restrict__ o) {
  const int blk = blockIdx.x;         // 0..255
  const int bh = blk >> 2;
  const int b = bh >> 4, h = bh & 15;
  const int dvc = blk & 3;
  const int t = threadIdx.x;
  const int dvl = t >> 3;
  const int dkg = t & 7;
  const int dv = dvc * 32 + dvl;

  const long m0 = (long)b * 2048;
  const ushort* qp = qkvg + m0 * 6144 + h * 64 + dkg * 8;
  const ushort* kp = qp + 1024;
  const ushort* vp = qkvg + m0 * 6144 + 2048 + h * 128 + dv;
  const float* gp = eg + m0 * 1024 + h * 64 + dkg * 8;
  float* op = o + m0 * 2048 + h * 128 + dv;

  float S[8];
#pragma unroll
  for (int i = 0; i < 8; ++i) S[i] = 0.f;

  uint4 qv = *(const uint4*)qp;
  uint4 kv = *(const uint4*)kp;
  float4 g0 = *(const float4*)gp;
  float4 g1 = *(const float4*)(gp + 4);
  ushort vv = *vp;

  for (int tt = 0; tt < 2048; ++tt) {
    qp += 6144; kp += 6144; vp += 6144; gp += 1024;
    // prefetch next step (last iter reads one row past — lands in later ws buffers, safe)
    uint4 qn = *(const uint4*)qp;
    uint4 kn = *(const uint4*)kp;
    float4 gn0 = *(const float4*)gp;
    float4 gn1 = *(const float4*)(gp + 4);
    ushort vn = *vp;

    float qf[8], kf[8];
    unpack8(qv, qf);
    unpack8(kv, kf);
    float gc[8] = {g0.x, g0.y, g0.z, g0.w, g1.x, g1.y, g1.z, g1.w};
    const float vf = bf2f(vv);
    float part = 0.f;
#pragma unroll
    for (int i = 0; i < 8; ++i) {
      S[i] = S[i] * gc[i] + kf[i] * vf;
      part += qf[i] * S[i];
    }
    part *= 0.125f;  // DK^-0.5
    part += __shfl_xor(part, 1);
    part += __shfl_xor(part, 2);
    part += __shfl_xor(part, 4);
    if (dkg == 0) *op = part;
    op += 2048;
    qv = qn; kv = kn; g0 = gn0; g1 = gn1; vv = vn;
  }
}

// ---------------- RMSNorm * norm_w * swish(g) -> oo bf16 ----------------
__global__ __launch_bounds__(256) void normgate_kernel(
    const float* __restrict__ o, const ushort* __restrict__ qkvg,
    const float* __restrict__ norm_w, ushort* __restrict__ oo) {
  const int m = blockIdx.x;
  const int t = threadIdx.x;
  const int h = t >> 4;
  const int i8 = (t & 15) * 8;
  const float* orow = o + (long)m * 2048 + h * 128 + i8;
  float4 a0 = *(const float4*)orow;
  float4 a1 = *(const float4*)(orow + 4);
  float vs[8] = {a0.x, a0.y, a0.z, a0.w, a1.x, a1.y, a1.z, a1.w};
  float ss = 0.f;
#pragma unroll
  for (int i = 0; i < 8; ++i) ss += vs[i] * vs[i];
#pragma unroll
  for (int d = 1; d < 16; d <<= 1) ss += __shfl_xor(ss, d);
  const float inv = rsqrtf(ss * (1.f / 128.f) + 1e-5f);
  const ushort* grow = qkvg + (long)m * 6144 + 4096 + h * 128 + i8;
  uint4 gv = *(const uint4*)grow;
  float gf[8];
  unpack8(gv, gf);
  float4 w0 = *(const float4*)(norm_w + i8);
  float4 w1 = *(const float4*)(norm_w + i8 + 4);
  float wf[8] = {w0.x, w0.y, w0.z, w0.w, w1.x, w1.y, w1.z, w1.w};
  float r[8];
#pragma unroll
  for (int i = 0; i < 8; ++i) {
    float g = gf[i];
    float sw = g / (1.f + __expf(-g));      // g*sigmoid(g)
    r[i] = vs[i] * inv * wf[i] * sw;
  }
  uint4 ov;
  ov.x = pack2(r[0], r[1]); ov.y = pack2(r[2], r[3]);
  ov.z = pack2(r[4], r[5]); ov.w = pack2(r[6], r[7]);
  *(uint4*)(oo + (long)m * 2048 + h * 128 + i8) = ov;
}

extern "C" void kernel_launch(void* const* d_in, const int* in_sizes, int n_in,
                              void* d_out, int out_size, void* d_ws, size_t ws_size,
                              hipStream_t stream) {
  const float* x      = (const float*)d_in[0];
  const float* Wq     = (const float*)d_in[1];
  const float* Wk     = (const float*)d_in[2];
  const float* Wv     = (const float*)d_in[3];
  const float* Wg     = (const float*)d_in[4];
  const float* Wgk1   = (const float*)d_in[5];
  const float* Wgk2   = (const float*)d_in[6];
  const float* bgk2   = (const float*)d_in[7];
  const float* norm_w = (const float*)d_in[8];
  const float* Wo     = (const float*)d_in[9];
  float* out = (float*)d_out;

  char* ws = (char*)d_ws;
  ushort* WT   = (ushort*)(ws);                       // [6144][2048] bf16   25165824 B
  ushort* WoT  = (ushort*)(ws + 25165824);            // [2048][2048] bf16    8388608 B
  ushort* qkvg = (ushort*)(ws + 33554432);            // [8192][6144] bf16  100663296 B
  float*  eg   = (float*)(ws + 134217728);            // [8192][1024] f32    33554432 B
  float*  obuf = (float*)(ws + 167772160);            // [8192][2048] f32    67108864 B
  ushort* xb   = (ushort*)(ws + 234881024);           // [8192][2048] bf16   33554432 B
  ushort* oo   = xb;  // overlay: xb dead after gemm1; oo written after (stream-ordered)
  // total 268435456 B = 256 MiB

  dim3 blk(256);
  f32_to_bf16<<<dim3(8192), blk, 0, stream>>>(x, xb, (long)8192 * 2048);
  transpose_f32_bf16<<<dim3(16, 32), blk, 0, stream>>>(Wq, WT, 2048, 1024);
  transpose_f32_bf16<<<dim3(16, 32), blk, 0, stream>>>(Wk, WT + (size_t)1024 * 2048, 2048, 1024);
  transpose_f32_bf16<<<dim3(32, 32), blk, 0, stream>>>(Wv, WT + (size_t)2048 * 2048, 2048, 2048);
  transpose_f32_bf16<<<dim3(32, 32), blk, 0, stream>>>(Wg, WT + (size_t)4096 * 2048, 2048, 2048);
  transpose_f32_bf16<<<dim3(32, 32), blk, 0, stream>>>(Wo, WoT, 2048, 2048);

  gemm_bt<ushort><<<dim3(48, 64), blk, 0, stream>>>(xb, WT, qkvg, 8192, 6144, 2048);
  gate_kernel<<<dim3(8192), blk, 0, stream>>>(x, Wgk1, Wgk2, bgk2, eg);
  scan_kernel<<<dim3(256), blk, 0, stream>>>(qkvg, eg, obuf);
  normgate_kernel<<<dim3(8192), blk, 0, stream>>>(obuf, qkvg, norm_w, oo);
  gemm_bt<float><<<dim3(16, 64), blk, 0, stream>>>(oo, WoT, out, 8192, 2048, 2048);
}

// Round 3
// 610.766 us; speedup vs baseline: 2.4071x; 2.4071x over previous
//
#include <hip/hip_runtime.h>
#include <hip/hip_bf16.h>
#include <type_traits>

// GLA attention forward: B=4,T=2048,D=2048,H=16,DK=64,DV=128,LR=16
// Inputs/outputs are float32. bf16 internally for MFMA.
// Chunked GLA: chunk=64; intra-chunk via MFMA, inter-chunk via 32-step chunk scan.

using bf16x8 = __attribute__((ext_vector_type(8))) short;
using f32x4  = __attribute__((ext_vector_type(4))) float;

static __device__ __forceinline__ float bf2f(ushort u) {
  union { unsigned int i; float f; } v;
  v.i = ((unsigned int)u) << 16;
  return v.f;
}
static __device__ __forceinline__ ushort f2bf(float f) {
  __hip_bfloat16 h = __float2bfloat16(f);
  return *reinterpret_cast<ushort*>(&h);
}
static __device__ __forceinline__ unsigned int pack2(float lo, float hi) {
  return (unsigned int)f2bf(lo) | ((unsigned int)f2bf(hi) << 16);
}
static __device__ __forceinline__ void unpack8(uint4 v, float* f) {
  f[0] = bf2f((ushort)(v.x & 0xffff)); f[1] = bf2f((ushort)(v.x >> 16));
  f[2] = bf2f((ushort)(v.y & 0xffff)); f[3] = bf2f((ushort)(v.y >> 16));
  f[4] = bf2f((ushort)(v.z & 0xffff)); f[5] = bf2f((ushort)(v.z >> 16));
  f[6] = bf2f((ushort)(v.w & 0xffff)); f[7] = bf2f((ushort)(v.w >> 16));
}

#define GLDS16(g, l) __builtin_amdgcn_global_load_lds( \
    (const __attribute__((address_space(1))) unsigned int*)(g), \
    (__attribute__((address_space(3))) unsigned int*)(l), 16, 0, 0)

// ---------------- f32 -> bf16 elementwise ----------------
__global__ __launch_bounds__(256) void f32_to_bf16(
    const float* __restrict__ in, ushort* __restrict__ out, long n) {
  long i = ((long)blockIdx.x * 256 + threadIdx.x) * 8;
  if (i >= n) return;
  float4 a = *(const float4*)(in + i);
  float4 b = *(const float4*)(in + i + 4);
  uint4 o;
  o.x = pack2(a.x, a.y); o.y = pack2(a.z, a.w);
  o.z = pack2(b.x, b.y); o.w = pack2(b.z, b.w);
  *(uint4*)(out + i) = o;
}

// ---------------- transpose f32 in[R][C] -> bf16 out[C][R] ----------------
__global__ __launch_bounds__(256) void transpose_f32_bf16(
    const float* __restrict__ in, ushort* __restrict__ out, int R, int C) {
  __shared__ float tile[64][65];
  const int t = threadIdx.x;
  const int tc = blockIdx.x * 64;
  const int tr = blockIdx.y * 64;
  const int lr = t >> 2;
  const int lc = (t & 3) * 16;
  const float* ip = in + (long)(tr + lr) * C + tc + lc;
#pragma unroll
  for (int j = 0; j < 4; ++j)
    *(float4*)(&tile[lr][lc + j * 4]) = *(const float4*)(ip + j * 4);
  __syncthreads();
  const int c = t >> 2;
  const int r0 = (t & 3) * 16;
  ushort tmp[16];
#pragma unroll
  for (int j = 0; j < 16; ++j) tmp[j] = f2bf(tile[r0 + j][c]);
  ushort* op = out + (long)(tc + c) * R + tr + r0;
  *(uint4*)(op)     = *(uint4*)(tmp);
  *(uint4*)(op + 8) = *(uint4*)(tmp + 8);
}

// ---------------- GEMM: C[M][N] = A[M][K] * BT[N][K]^T ----------------
template <typename OT>
__global__ __launch_bounds__(256) void gemm_bt(
    const ushort* __restrict__ A, const ushort* __restrict__ BT,
    OT* __restrict__ C, int M, int N, int K) {
  __shared__ ushort sA[128 * 32];
  __shared__ ushort sB[128 * 32];
  const int t = threadIdx.x;
  const int brow = blockIdx.y * 128;
  const int bcol = blockIdx.x * 128;
  const int w = t >> 6, l = t & 63;
  const int wr = (w >> 1) * 64, wc = (w & 1) * 64;
  const int lr = l & 15;
  const int kq = (l >> 4) * 8;

  f32x4 acc[4][4];
#pragma unroll
  for (int m = 0; m < 4; ++m)
#pragma unroll
    for (int n = 0; n < 4; ++n) acc[m][n] = (f32x4){0.f, 0.f, 0.f, 0.f};

  const int r0 = t >> 2;
  const int kk0 = (t & 3) << 3;
  const ushort* Ag  = A  + (long)(brow + r0) * K + kk0;
  const ushort* Ag2 = A  + (long)(brow + 64 + r0) * K + kk0;
  const ushort* Bg  = BT + (long)(bcol + r0) * K + kk0;
  const ushort* Bg2 = BT + (long)(bcol + 64 + r0) * K + kk0;
  ushort* sAp  = sA + t * 8;
  ushort* sAp2 = sA + (256 + t) * 8;
  ushort* sBp  = sB + t * 8;
  ushort* sBp2 = sB + (256 + t) * 8;

  for (int k0 = 0; k0 < K; k0 += 32) {
    __syncthreads();
    GLDS16(Ag + k0, sAp);
    GLDS16(Ag2 + k0, sAp2);
    GLDS16(Bg + k0, sBp);
    GLDS16(Bg2 + k0, sBp2);
    __syncthreads();
    bf16x8 af[4], bfr[4];
#pragma unroll
    for (int m = 0; m < 4; ++m)
      af[m] = *(const bf16x8*)(sA + (wr + m * 16 + lr) * 32 + kq);
#pragma unroll
    for (int n = 0; n < 4; ++n)
      bfr[n] = *(const bf16x8*)(sB + (wc + n * 16 + lr) * 32 + kq);
#pragma unroll
    for (int m = 0; m < 4; ++m)
#pragma unroll
      for (int n = 0; n < 4; ++n)
        acc[m][n] = __builtin_amdgcn_mfma_f32_16x16x32_bf16(af[m], bfr[n], acc[m][n], 0, 0, 0);
  }

  const int rq = (l >> 4) * 4;
#pragma unroll
  for (int m = 0; m < 4; ++m)
#pragma unroll
    for (int n = 0; n < 4; ++n) {
      long row = brow + wr + m * 16 + rq;
      long col = bcol + wc + n * 16 + lr;
      OT* cp = C + row * N + col;
#pragma unroll
      for (int r = 0; r < 4; ++r) {
        if constexpr (std::is_same_v<OT, ushort>) cp[(long)r * N] = f2bf(acc[m][n][r]);
        else                                      cp[(long)r * N] = acc[m][n][r];
      }
    }
}

// ---------------- gate path: gbuf[m][1024] = bf16( logsigmoid((x@Wgk1)@Wgk2+b)/16 ) ----------------
__global__ __launch_bounds__(256) void gate_kernel(
    const float* __restrict__ x, const float* __restrict__ Wgk1,
    const float* __restrict__ Wgk2, const float* __restrict__ bgk2,
    ushort* __restrict__ gbuf) {
  const int m = blockIdx.x;
  const int t = threadIdx.x;
  __shared__ float sx[2048];
  __shared__ float red[256];
  __shared__ float z1[16];
  const float* xr = x + (long)m * 2048;
  *(float4*)(sx + t * 8)     = *(const float4*)(xr + t * 8);
  *(float4*)(sx + t * 8 + 4) = *(const float4*)(xr + t * 8 + 4);
  __syncthreads();
  const int j = t & 15, seg = t >> 4;
  float s = 0.f;
  for (int d = 0; d < 128; ++d)
    s += sx[seg * 128 + d] * Wgk1[(seg * 128 + d) * 16 + j];
  red[t] = s;
  __syncthreads();
  if (t < 16) {
    float z = 0.f;
    for (int sg = 0; sg < 16; ++sg) z += red[sg * 16 + t];
    z1[t] = z;
  }
  __syncthreads();
#pragma unroll
  for (int r = 0; r < 4; ++r) {
    int n = r * 256 + t;
    float a = bgk2[n];
#pragma unroll
    for (int l2 = 0; l2 < 16; ++l2) a += z1[l2] * Wgk2[l2 * 1024 + n];
    float ls = fminf(a, 0.f) - log1pf(__expf(-fabsf(a)));  // logsigmoid
    gbuf[(long)m * 1024 + n] = f2bf(ls * 0.0625f);
  }
}

// ---------------- Phase A: per-chunk state contribution ----------------
// block = (bh, chunk). contrib[k][dv] = sum_s k[s][k]*exp(Gtot[k]-gc[s][k]) * v[s][dv]
__global__ __launch_bounds__(256) void chunk_contrib_kernel(
    const ushort* __restrict__ qkvg, const ushort* __restrict__ gbuf,
    float* __restrict__ Sall, float* __restrict__ Gtot) {
  const int blk = blockIdx.x;           // 2048 = bh*32 + c
  const int bh = blk >> 5, c = blk & 31;
  const int b = bh >> 4, h = bh & 15;
  const long row0 = (long)b * 2048 + c * 64;
  const int th = threadIdx.x;

  __shared__ float  gc[64][65];
  __shared__ ushort khT[64][72];
  __shared__ ushort vT[128][72];

  {  // load gk tile (bf16 -> f32)
    const int t = th >> 2;
    const int k0 = (th & 3) * 16;
    const ushort* gp = gbuf + (row0 + t) * 1024 + h * 64 + k0;
    uint4 a = *(const uint4*)gp;
    uint4 b4 = *(const uint4*)(gp + 8);
    float f[8];
    unpack8(a, f);
#pragma unroll
    for (int j = 0; j < 8; ++j) gc[t][k0 + j] = f[j];
    unpack8(b4, f);
#pragma unroll
    for (int j = 0; j < 8; ++j) gc[t][k0 + 8 + j] = f[j];
  }
  __syncthreads();
  if (th < 64) {  // inclusive cumsum over t per column
    float s = 0.f;
    for (int t = 0; t < 64; ++t) { s += gc[t][th]; gc[t][th] = s; }
  }
  __syncthreads();
  if (th < 64) Gtot[(long)blk * 64 + th] = gc[63][th];

  {  // khT[k][s], vT[dv][s]
    const int s = th & 63, kq = th >> 6;
    const ushort* kp = qkvg + (row0 + s) * 6144 + 1024 + h * 64 + kq * 16;
    uint4 a = *(const uint4*)kp;
    uint4 b4 = *(const uint4*)(kp + 8);
    float f[16];
    unpack8(a, f); unpack8(b4, f + 8);
    const float gt_base = gc[63][0];  // dummy to keep compiler happy
    (void)gt_base;
#pragma unroll
    for (int j = 0; j < 16; ++j) {
      int k = kq * 16 + j;
      khT[k][s] = f2bf(f[j] * __expf(gc[63][k] - gc[s][k]));
    }
    const ushort* vp = qkvg + (row0 + s) * 6144 + 2048 + h * 128 + kq * 32;
#pragma unroll
    for (int u = 0; u < 4; ++u) {
      uint4 vv = *(const uint4*)(vp + u * 8);
      const ushort* pv = (const ushort*)&vv;
#pragma unroll
      for (int j = 0; j < 8; ++j) vT[kq * 32 + u * 8 + j][s] = pv[j];
    }
  }
  __syncthreads();

  // contrib = khT[64k x 64s] @ v[64s x 128dv]; wave w owns dv range w*32
  const int w = th >> 6, l = th & 63;
  const int lr = l & 15, kq8 = (l >> 4) * 8;
  f32x4 acc[4][2];
#pragma unroll
  for (int m = 0; m < 4; ++m)
#pragma unroll
    for (int n = 0; n < 2; ++n) acc[m][n] = (f32x4){0.f, 0.f, 0.f, 0.f};
#pragma unroll
  for (int ks = 0; ks < 64; ks += 32) {
#pragma unroll
    for (int m = 0; m < 4; ++m) {
      bf16x8 af = *(const bf16x8*)(&khT[m * 16 + lr][ks + kq8]);
#pragma unroll
      for (int n = 0; n < 2; ++n) {
        bf16x8 bv = *(const bf16x8*)(&vT[w * 32 + n * 16 + lr][ks + kq8]);
        acc[m][n] = __builtin_amdgcn_mfma_f32_16x16x32_bf16(af, bv, acc[m][n], 0, 0, 0);
      }
    }
  }
  float* Cc = Sall + (long)blk * 8192;   // [64][128] f32
  const int rq = (l >> 4) * 4;
#pragma unroll
  for (int m = 0; m < 4; ++m)
#pragma unroll
    for (int n = 0; n < 2; ++n) {
      int k = m * 16 + rq;
      int dv = w * 32 + n * 16 + lr;
#pragma unroll
      for (int r = 0; r < 4; ++r) Cc[(k + r) * 128 + dv] = acc[m][n][r];
    }
}

// ---------------- Phase B: sequential scan over 32 chunks ----------------
// Sall[bh][c] holds contrib on entry; on exit holds S_in (state BEFORE chunk c).
__global__ __launch_bounds__(256) void chunk_scan_kernel(
    float* __restrict__ Sall, const float* __restrict__ Gtot) {
  const int blk = blockIdx.x;      // 256 = bh*4 + quarter
  const int bh = blk >> 2, qd = blk & 3;
  const int th = threadIdx.x;
  const int k = th >> 2;
  const int dv = qd * 32 + (th & 3) * 8;
  float* base = Sall + (long)bh * 32 * 8192 + k * 128 + dv;
  const float* gt = Gtot + (long)bh * 32 * 64 + k;
  float S[8];
#pragma unroll
  for (int i = 0; i < 8; ++i) S[i] = 0.f;
  for (int c = 0; c < 32; ++c) {
    float4 c0 = *(const float4*)(base);
    float4 c1 = *(const float4*)(base + 4);
    float eg = __expf(gt[c * 64]);
    float4 s0 = {S[0], S[1], S[2], S[3]};
    float4 s1 = {S[4], S[5], S[6], S[7]};
    *(float4*)(base) = s0;
    *(float4*)(base + 4) = s1;
    S[0] = S[0] * eg + c0.x; S[1] = S[1] * eg + c0.y;
    S[2] = S[2] * eg + c0.z; S[3] = S[3] * eg + c0.w;
    S[4] = S[4] * eg + c1.x; S[5] = S[5] * eg + c1.y;
    S[6] = S[6] * eg + c1.z; S[7] = S[7] * eg + c1.w;
    base += 8192;
  }
}

// ---------------- Phase C: chunk output + fused RMSNorm*swish gate ----------------
__global__ __launch_bounds__(256) void chunk_output_kernel(
    const ushort* __restrict__ qkvg, const ushort* __restrict__ gbuf,
    const float* __restrict__ Sall, const float* __restrict__ norm_w,
    ushort* __restrict__ oo) {
  const int blk = blockIdx.x;           // 2048
  const int bh = blk >> 5, c = blk & 31;
  const int b = bh >> 4, h = bh & 15;
  const long row0 = (long)b * 2048 + c * 64;
  const int th = threadIdx.x;

  __shared__ float  gc[64][65];
  __shared__ ushort qg[64][72];
  __shared__ ushort kg[64][72];
  __shared__ ushort vT[128][72];
  __shared__ ushort ST[128][72];
  __shared__ ushort P[64][72];
  __shared__ ushort ot[64][136];   // gate tile, then output tile (in-place)

  {  // loads: gk->gc, q->qg raw, k->kg raw, v->vT, gate->ot, S_in->ST
    const int t = th >> 2;
    const int s4 = (th & 3);
    const int k0 = s4 * 16;
    const ushort* gp = gbuf + (row0 + t) * 1024 + h * 64 + k0;
    uint4 a = *(const uint4*)gp;
    uint4 b4 = *(const uint4*)(gp + 8);
    float f[8];
    unpack8(a, f);
#pragma unroll
    for (int j = 0; j < 8; ++j) gc[t][k0 + j] = f[j];
    unpack8(b4, f);
#pragma unroll
    for (int j = 0; j < 8; ++j) gc[t][k0 + 8 + j] = f[j];

    const ushort* qp = qkvg + (row0 + t) * 6144 + h * 64 + k0;
    *(uint4*)(&qg[t][k0])     = *(const uint4*)qp;
    *(uint4*)(&qg[t][k0 + 8]) = *(const uint4*)(qp + 8);
    const ushort* kp = qp + 1024;
    *(uint4*)(&kg[t][k0])     = *(const uint4*)kp;
    *(uint4*)(&kg[t][k0 + 8]) = *(const uint4*)(kp + 8);

    const ushort* gtp = qkvg + (row0 + t) * 6144 + 4096 + h * 128 + s4 * 32;
#pragma unroll
    for (int u = 0; u < 4; ++u)
      *(uint4*)(&ot[t][s4 * 32 + u * 8]) = *(const uint4*)(gtp + u * 8);
  }
  {  // v transpose
    const int s = th & 63, kq = th >> 6;
    const ushort* vp = qkvg + (row0 + s) * 6144 + 2048 + h * 128 + kq * 32;
#pragma unroll
    for (int u = 0; u < 4; ++u) {
      uint4 vv = *(const uint4*)(vp + u * 8);
      const ushort* pv = (const ushort*)&vv;
#pragma unroll
      for (int j = 0; j < 8; ++j) vT[kq * 32 + u * 8 + j][s] = pv[j];
    }
  }
  {  // S_in transpose (f32 -> bf16)
    const int k = th >> 2;
    const int dvb = (th & 3) * 32;
    const float* sp = Sall + (long)blk * 8192 + k * 128 + dvb;
#pragma unroll
    for (int u = 0; u < 8; ++u) {
      float4 sv = *(const float4*)(sp + u * 4);
      ST[dvb + u * 4 + 0][k] = f2bf(sv.x);
      ST[dvb + u * 4 + 1][k] = f2bf(sv.y);
      ST[dvb + u * 4 + 2][k] = f2bf(sv.z);
      ST[dvb + u * 4 + 3][k] = f2bf(sv.w);
    }
  }
  __syncthreads();
  if (th < 64) {  // cumsum
    float s = 0.f;
    for (int t = 0; t < 64; ++t) { s += gc[t][th]; gc[t][th] = s; }
  }
  __syncthreads();
  {  // apply exp: qg *= exp(gc)*scale ; kg *= exp(-gc)
    const int t = th & 63, kb = (th >> 6) * 16;
#pragma unroll
    for (int u = 0; u < 2; ++u) {
      uint4 qv = *(const uint4*)(&qg[t][kb + u * 8]);
      uint4 kv = *(const uint4*)(&kg[t][kb + u * 8]);
      float qf[8], kf[8];
      unpack8(qv, qf); unpack8(kv, kf);
      ushort qo[8], ko[8];
#pragma unroll
      for (int j = 0; j < 8; ++j) {
        float g = gc[t][kb + u * 8 + j];
        qo[j] = f2bf(qf[j] * __expf(g) * 0.125f);
        ko[j] = f2bf(kf[j] * __expf(-g));
      }
      *(uint4*)(&qg[t][kb + u * 8]) = *(uint4*)qo;
      *(uint4*)(&kg[t][kb + u * 8]) = *(uint4*)ko;
    }
  }
  __syncthreads();

  const int w = th >> 6, l = th & 63;
  const int lr = l & 15, kq8 = (l >> 4) * 8;
  const int rq = (l >> 4) * 4;

  // A1 = qg @ kg^T : [64t][64s], wave w owns rows w*16..+15
  f32x4 acc1[4];
#pragma unroll
  for (int n = 0; n < 4; ++n) acc1[n] = (f32x4){0.f, 0.f, 0.f, 0.f};
#pragma unroll
  for (int kk = 0; kk < 64; kk += 32) {
    bf16x8 af = *(const bf16x8*)(&qg[w * 16 + lr][kk + kq8]);
#pragma unroll
    for (int n = 0; n < 4; ++n) {
      bf16x8 bv = *(const bf16x8*)(&kg[n * 16 + lr][kk + kq8]);
      acc1[n] = __builtin_amdgcn_mfma_f32_16x16x32_bf16(af, bv, acc1[n], 0, 0, 0);
    }
  }
  // causal mask, write P
#pragma unroll
  for (int n = 0; n < 4; ++n) {
    int s = n * 16 + lr;
#pragma unroll
    for (int r = 0; r < 4; ++r) {
      int t = w * 16 + rq + r;
      P[t][s] = f2bf(s <= t ? acc1[n][r] : 0.f);
    }
  }
  __syncthreads();

  // O = P @ v + qg @ S_in : [64t][128dv], wave w owns rows w*16..+15
  f32x4 acc2[8];
#pragma unroll
  for (int n = 0; n < 8; ++n) acc2[n] = (f32x4){0.f, 0.f, 0.f, 0.f};
#pragma unroll
  for (int ks = 0; ks < 64; ks += 32) {
    bf16x8 af = *(const bf16x8*)(&P[w * 16 + lr][ks + kq8]);
#pragma unroll
    for (int n = 0; n < 8; ++n) {
      bf16x8 bv = *(const bf16x8*)(&vT[n * 16 + lr][ks + kq8]);
      acc2[n] = __builtin_amdgcn_mfma_f32_16x16x32_bf16(af, bv, acc2[n], 0, 0, 0);
    }
  }
#pragma unroll
  for (int kk = 0; kk < 64; kk += 32) {
    bf16x8 af = *(const bf16x8*)(&qg[w * 16 + lr][kk + kq8]);
#pragma unroll
    for (int n = 0; n < 8; ++n) {
      bf16x8 bv = *(const bf16x8*)(&ST[n * 16 + lr][kk + kq8]);
      acc2[n] = __builtin_amdgcn_mfma_f32_16x16x32_bf16(af, bv, acc2[n], 0, 0, 0);
    }
  }

  // fused RMSNorm(dv=128) * norm_w * swish(gate)
  float sumsq[4] = {0.f, 0.f, 0.f, 0.f};
#pragma unroll
  for (int n = 0; n < 8; ++n)
#pragma unroll
    for (int r = 0; r < 4; ++r) sumsq[r] += acc2[n][r] * acc2[n][r];
#pragma unroll
  for (int d = 1; d < 16; d <<= 1)
#pragma unroll
    for (int r = 0; r < 4; ++r) sumsq[r] += __shfl_xor(sumsq[r], d);
  float inv[4];
#pragma unroll
  for (int r = 0; r < 4; ++r) inv[r] = rsqrtf(sumsq[r] * (1.f / 128.f) + 1e-5f);

#pragma unroll
  for (int n = 0; n < 8; ++n) {
    int dv = n * 16 + lr;
    float nw = norm_w[dv];
#pragma unroll
    for (int r = 0; r < 4; ++r) {
      int t = w * 16 + rq + r;
      float g = bf2f(ot[t][dv]);
      float sw = g / (1.f + __expf(-g));
      ot[t][dv] = f2bf(acc2[n][r] * inv[r] * nw * sw);
    }
  }
  __syncthreads();

  {  // coalesced write-out
    const int row = th >> 2;
    const int col0 = (th & 3) * 32;
    ushort* op = oo + (row0 + row) * 2048 + h * 128 + col0;
#pragma unroll
    for (int u = 0; u < 4; ++u)
      *(uint4*)(op + u * 8) = *(const uint4*)(&ot[row][col0 + u * 8]);
  }
}

extern "C" void kernel_launch(void* const* d_in, const int* in_sizes, int n_in,
                              void* d_out, int out_size, void* d_ws, size_t ws_size,
                              hipStream_t stream) {
  const float* x      = (const float*)d_in[0];
  const float* Wq     = (const float*)d_in[1];
  const float* Wk     = (const float*)d_in[2];
  const float* Wv     = (const float*)d_in[3];
  const float* Wg     = (const float*)d_in[4];
  const float* Wgk1   = (const float*)d_in[5];
  const float* Wgk2   = (const float*)d_in[6];
  const float* bgk2   = (const float*)d_in[7];
  const float* norm_w = (const float*)d_in[8];
  const float* Wo     = (const float*)d_in[9];
  float* out = (float*)d_out;

  char* ws = (char*)d_ws;
  ushort* WT   = (ushort*)(ws);                        // [6144][2048] bf16  25,165,824
  ushort* WoT  = (ushort*)(ws + 25165824);             // [2048][2048] bf16   8,388,608
  ushort* qkvg = (ushort*)(ws + 33554432);             // [8192][6144] bf16 100,663,296
  ushort* gbuf = (ushort*)(ws + 134217728);            // [8192][1024] bf16  16,777,216
  float*  Sall = (float*)(ws + 150994944);             // [2048][64][128] f32 67,108,864
  ushort* xb   = (ushort*)(ws + 150994944);            // overlay: dead after gemm1
  float*  Gtot = (float*)(ws + 218103808);             // [2048][64] f32        524,288
  ushort* oo   = (ushort*)(ws + 218628096);            // [8192][2048] bf16  33,554,432
  // end: 252,182,528 < 256 MiB

  dim3 blk(256);
  f32_to_bf16<<<dim3(8192), blk, 0, stream>>>(x, xb, (long)8192 * 2048);
  transpose_f32_bf16<<<dim3(16, 32), blk, 0, stream>>>(Wq, WT, 2048, 1024);
  transpose_f32_bf16<<<dim3(16, 32), blk, 0, stream>>>(Wk, WT + (size_t)1024 * 2048, 2048, 1024);
  transpose_f32_bf16<<<dim3(32, 32), blk, 0, stream>>>(Wv, WT + (size_t)2048 * 2048, 2048, 2048);
  transpose_f32_bf16<<<dim3(32, 32), blk, 0, stream>>>(Wg, WT + (size_t)4096 * 2048, 2048, 2048);
  transpose_f32_bf16<<<dim3(32, 32), blk, 0, stream>>>(Wo, WoT, 2048, 2048);

  gemm_bt<ushort><<<dim3(48, 64), blk, 0, stream>>>(xb, WT, qkvg, 8192, 6144, 2048);
  gate_kernel<<<dim3(8192), blk, 0, stream>>>(x, Wgk1, Wgk2, bgk2, gbuf);

  chunk_contrib_kernel<<<dim3(2048), blk, 0, stream>>>(qkvg, gbuf, Sall, Gtot);
  chunk_scan_kernel<<<dim3(256), blk, 0, stream>>>(Sall, Gtot);
  chunk_output_kernel<<<dim3(2048), blk, 0, stream>>>(qkvg, gbuf, Sall, norm_w, oo);

  gemm_bt<float><<<dim3(16, 64), blk, 0, stream>>>(oo, WoT, out, 8192, 2048, 2048);
}

// Round 4
// 526.014 us; speedup vs baseline: 2.7950x; 1.1611x over previous
//
#include <hip/hip_runtime.h>
#include <hip/hip_bf16.h>
#include <type_traits>

// GLA attention forward: B=4,T=2048,D=2048,H=16,DK=64,DV=128,LR=16
// Inputs/outputs are float32. bf16 internally for MFMA.
// Chunked GLA (chunk=64) + 256^2 8-phase GEMM (T1+T2+T3/T4+T5).

using bf16x8 = __attribute__((ext_vector_type(8))) short;
using f32x4  = __attribute__((ext_vector_type(4))) float;

static __device__ __forceinline__ float bf2f(ushort u) {
  union { unsigned int i; float f; } v;
  v.i = ((unsigned int)u) << 16;
  return v.f;
}
static __device__ __forceinline__ ushort f2bf(float f) {
  __hip_bfloat16 h = __float2bfloat16(f);
  return *reinterpret_cast<ushort*>(&h);
}
static __device__ __forceinline__ unsigned int pack2(float lo, float hi) {
  return (unsigned int)f2bf(lo) | ((unsigned int)f2bf(hi) << 16);
}
static __device__ __forceinline__ void unpack8(uint4 v, float* f) {
  f[0] = bf2f((ushort)(v.x & 0xffff)); f[1] = bf2f((ushort)(v.x >> 16));
  f[2] = bf2f((ushort)(v.y & 0xffff)); f[3] = bf2f((ushort)(v.y >> 16));
  f[4] = bf2f((ushort)(v.z & 0xffff)); f[5] = bf2f((ushort)(v.z >> 16));
  f[6] = bf2f((ushort)(v.w & 0xffff)); f[7] = bf2f((ushort)(v.w >> 16));
}

#define GLDS16(g, l) __builtin_amdgcn_global_load_lds( \
    (const __attribute__((address_space(1))) unsigned int*)(g), \
    (__attribute__((address_space(3))) unsigned int*)(l), 16, 0, 0)

// ---------------- f32 -> bf16 elementwise ----------------
__global__ __launch_bounds__(256) void f32_to_bf16(
    const float* __restrict__ in, ushort* __restrict__ out, long n) {
  long i = ((long)blockIdx.x * 256 + threadIdx.x) * 8;
  if (i >= n) return;
  float4 a = *(const float4*)(in + i);
  float4 b = *(const float4*)(in + i + 4);
  uint4 o;
  o.x = pack2(a.x, a.y); o.y = pack2(a.z, a.w);
  o.z = pack2(b.x, b.y); o.w = pack2(b.z, b.w);
  *(uint4*)(out + i) = o;
}

// ---------------- transpose f32 in[R][C] -> bf16 out[C][R] ----------------
__global__ __launch_bounds__(256) void transpose_f32_bf16(
    const float* __restrict__ in, ushort* __restrict__ out, int R, int C) {
  __shared__ float tile[64][65];
  const int t = threadIdx.x;
  const int tc = blockIdx.x * 64;
  const int tr = blockIdx.y * 64;
  const int lr = t >> 2;
  const int lc = (t & 3) * 16;
  const float* ip = in + (long)(tr + lr) * C + tc + lc;
#pragma unroll
  for (int j = 0; j < 4; ++j)
    *(float4*)(&tile[lr][lc + j * 4]) = *(const float4*)(ip + j * 4);
  __syncthreads();
  const int c = t >> 2;
  const int r0 = (t & 3) * 16;
  ushort tmp[16];
#pragma unroll
  for (int j = 0; j < 16; ++j) tmp[j] = f2bf(tile[r0 + j][c]);
  ushort* op = out + (long)(tc + c) * R + tr + r0;
  *(uint4*)(op)     = *(uint4*)(tmp);
  *(uint4*)(op + 8) = *(uint4*)(tmp + 8);
}

// ---------------- 256x256 8-phase GEMM: C[M][N] = A[M][K] * BT[N][K]^T ----------------
// BM=BN=256, BK=64, 512 thr = 8 waves (2m x 4n). Per-wave C: rows mq*32+wm*16 (mq 0..7),
// cols nq*64+wn*16 (nq 0..3). Phase (mh,nh) touches A-half mh, B-half nh only.
// LDS 128 KiB: A,B each 2buf x [256][64] bf16, st_16x32 swizzle (slot ^= ((row>>2)&1)<<1).
// Staging order per K-tile: A.h0,B.h0,B.h1,A.h1; phase p stages {kt+1.Ah1, kt+2.Ah0,
// kt+2.Bh0, kt+2.Bh1}; boundary s_waitcnt vmcnt(6) forces kt+1 complete (never 0 mid-loop).
template <typename OT>
__global__ __launch_bounds__(512, 2) void gemm_bt8(
    const ushort* __restrict__ A, const ushort* __restrict__ BT,
    OT* __restrict__ C, int M, int N, int K) {
  __shared__ ushort sA[2 * 16384];
  __shared__ ushort sB[2 * 16384];
  const int t = threadIdx.x;
  const int nbx = N >> 8;
  // XCD-aware swizzle (gridDim.x % 8 == 0)
  const int cpx = gridDim.x >> 3;
  const int wg = ((int)blockIdx.x & 7) * cpx + ((int)blockIdx.x >> 3);
  const int brow = (wg / nbx) * 256;
  const int bcol = (wg % nbx) * 256;

  const int w = t >> 6, l = t & 63;
  const int wm = w >> 2, wn = w & 3;
  const int lr = l & 15, lk = l >> 4;
  const int NT = K >> 6;

  // staging: thread t covers LDS bytes [t*16, t*16+16) of a [256][64] half-pair;
  // inverse-swizzle the GLOBAL source slot so swizzled ds_reads see linear data.
  const int srow = t >> 3;                                   // row within 64-row load
  const int cswz = ((t & 7) ^ (((srow >> 2) & 1) << 1)) * 8; // element offset in row
  const ushort* Abase = A + (size_t)(brow + srow) * K + cswz;
  const ushort* Bbase = BT + (size_t)(bcol + srow) * K + cswz;
  const int t8 = t * 8;

  auto stageA = [&](int bb, int hh, int jt) {
    const ushort* s = Abase + (size_t)(hh * 128) * K + jt * 64;
    ushort* d = sA + bb * 16384 + hh * 8192 + t8;
    GLDS16(s, d);
    GLDS16(s + (size_t)64 * K, d + 4096);
  };
  auto stageB = [&](int bb, int hh, int jt) {
    const ushort* s = Bbase + (size_t)(hh * 128) * K + jt * 64;
    ushort* d = sB + bb * 16384 + hh * 8192 + t8;
    GLDS16(s, d);
    GLDS16(s + (size_t)64 * K, d + 4096);
  };

  // ds_read offsets (swizzled)
  const int swz = ((lr >> 2) & 1) << 1;
  const int ks0 = ((0 + lk) ^ swz) * 8;   // ks=0 slot
  const int ks1 = ((4 + lk) ^ swz) * 8;   // ks=1 slot
  const int aRd = (wm * 16 + lr) * 64;
  const int bRd = (wn * 16 + lr) * 64;

  f32x4 acc[8][4];
#pragma unroll
  for (int m = 0; m < 8; ++m)
#pragma unroll
    for (int n = 0; n < 4; ++n) acc[m][n] = (f32x4){0.f, 0.f, 0.f, 0.f};

  // prologue: K-tile 0 (4 halves) -> vmcnt(4) -> K-tile 1 first 3 halves -> vmcnt(6)
  stageA(0, 0, 0); stageB(0, 0, 0); stageB(0, 1, 0); stageA(0, 1, 0);
  asm volatile("s_waitcnt vmcnt(4)" ::: "memory");
  stageA(1, 0, 1); stageB(1, 0, 1); stageB(1, 1, 1);
  asm volatile("s_waitcnt vmcnt(6)" ::: "memory");
  __builtin_amdgcn_s_barrier();

  for (int kt = 0; kt < NT; ++kt) {
    const int bb = kt & 1;
    const int aOff = bb * 16384, bOff = bb * 16384;
    bf16x8 aF[4][2], bF[2][2][2];

    // ---- phase 0: (mh0, nh0); 12 ds_reads; stage kt+1.A.h1 ----
#pragma unroll
    for (int m = 0; m < 4; ++m) {
      aF[m][0] = *(const bf16x8*)(sA + aOff + aRd + m * 2048 + ks0);
      aF[m][1] = *(const bf16x8*)(sA + aOff + aRd + m * 2048 + ks1);
    }
#pragma unroll
    for (int n = 0; n < 2; ++n) {
      bF[0][n][0] = *(const bf16x8*)(sB + bOff + bRd + n * 4096 + ks0);
      bF[0][n][1] = *(const bf16x8*)(sB + bOff + bRd + n * 4096 + ks1);
    }
    if (kt + 1 < NT) stageA(bb ^ 1, 1, kt + 1);
    __builtin_amdgcn_s_barrier();
    __builtin_amdgcn_s_setprio(1);
#pragma unroll
    for (int m = 0; m < 4; ++m)
#pragma unroll
      for (int n = 0; n < 2; ++n) {
        acc[m][n] = __builtin_amdgcn_mfma_f32_16x16x32_bf16(aF[m][0], bF[0][n][0], acc[m][n], 0, 0, 0);
        acc[m][n] = __builtin_amdgcn_mfma_f32_16x16x32_bf16(aF[m][1], bF[0][n][1], acc[m][n], 0, 0, 0);
      }
    __builtin_amdgcn_s_setprio(0);
    __builtin_amdgcn_s_barrier();

    // ---- phase 1: (mh0, nh1); 4 ds_reads; stage kt+2.A.h0 ----
#pragma unroll
    for (int n = 0; n < 2; ++n) {
      bF[1][n][0] = *(const bf16x8*)(sB + bOff + 8192 + bRd + n * 4096 + ks0);
      bF[1][n][1] = *(const bf16x8*)(sB + bOff + 8192 + bRd + n * 4096 + ks1);
    }
    if (kt + 2 < NT) stageA(bb, 0, kt + 2);
    __builtin_amdgcn_s_barrier();
    __builtin_amdgcn_s_setprio(1);
#pragma unroll
    for (int m = 0; m < 4; ++m)
#pragma unroll
      for (int n = 0; n < 2; ++n) {
        acc[m][2 + n] = __builtin_amdgcn_mfma_f32_16x16x32_bf16(aF[m][0], bF[1][n][0], acc[m][2 + n], 0, 0, 0);
        acc[m][2 + n] = __builtin_amdgcn_mfma_f32_16x16x32_bf16(aF[m][1], bF[1][n][1], acc[m][2 + n], 0, 0, 0);
      }
    __builtin_amdgcn_s_setprio(0);
    __builtin_amdgcn_s_barrier();

    // ---- phase 2: (mh1, nh0); 8 ds_reads; stage kt+2.B.h0 ----
#pragma unroll
    for (int m = 0; m < 4; ++m) {
      aF[m][0] = *(const bf16x8*)(sA + aOff + 8192 + aRd + m * 2048 + ks0);
      aF[m][1] = *(const bf16x8*)(sA + aOff + 8192 + aRd + m * 2048 + ks1);
    }
    if (kt + 2 < NT) stageB(bb, 0, kt + 2);
    __builtin_amdgcn_s_barrier();
    __builtin_amdgcn_s_setprio(1);
#pragma unroll
    for (int m = 0; m < 4; ++m)
#pragma unroll
      for (int n = 0; n < 2; ++n) {
        acc[4 + m][n] = __builtin_amdgcn_mfma_f32_16x16x32_bf16(aF[m][0], bF[0][n][0], acc[4 + m][n], 0, 0, 0);
        acc[4 + m][n] = __builtin_amdgcn_mfma_f32_16x16x32_bf16(aF[m][1], bF[0][n][1], acc[4 + m][n], 0, 0, 0);
      }
    __builtin_amdgcn_s_setprio(0);
    __builtin_amdgcn_s_barrier();

    // ---- phase 3: (mh1, nh1); 0 ds_reads; stage kt+2.B.h1; boundary vmcnt ----
    if (kt + 2 < NT) stageB(bb, 1, kt + 2);
    __builtin_amdgcn_s_barrier();
    __builtin_amdgcn_s_setprio(1);
#pragma unroll
    for (int m = 0; m < 4; ++m)
#pragma unroll
      for (int n = 0; n < 2; ++n) {
        acc[4 + m][2 + n] = __builtin_amdgcn_mfma_f32_16x16x32_bf16(aF[m][0], bF[1][n][0], acc[4 + m][2 + n], 0, 0, 0);
        acc[4 + m][2 + n] = __builtin_amdgcn_mfma_f32_16x16x32_bf16(aF[m][1], bF[1][n][1], acc[4 + m][2 + n], 0, 0, 0);
      }
    __builtin_amdgcn_s_setprio(0);
    if (kt < NT - 2)       asm volatile("s_waitcnt vmcnt(6)" ::: "memory");
    else if (kt == NT - 2) asm volatile("s_waitcnt vmcnt(0)" ::: "memory");
    __builtin_amdgcn_s_barrier();
  }

  // epilogue: C/D layout col=lane&15, row=(lane>>4)*4+reg
  const int rq = lk * 4;
#pragma unroll
  for (int mq = 0; mq < 8; ++mq)
#pragma unroll
    for (int nq = 0; nq < 4; ++nq) {
      long row = brow + mq * 32 + wm * 16 + rq;
      long col = bcol + nq * 64 + wn * 16 + lr;
      OT* cp = C + row * N + col;
#pragma unroll
      for (int r = 0; r < 4; ++r) {
        if constexpr (std::is_same_v<OT, ushort>) cp[(long)r * N] = f2bf(acc[mq][nq][r]);
        else                                      cp[(long)r * N] = acc[mq][nq][r];
      }
    }
}

// ---------------- gate path: gbuf[m][1024] = bf16( logsigmoid((x@Wgk1)@Wgk2+b)/16 ) ----------------
__global__ __launch_bounds__(256) void gate_kernel(
    const float* __restrict__ x, const float* __restrict__ Wgk1,
    const float* __restrict__ Wgk2, const float* __restrict__ bgk2,
    ushort* __restrict__ gbuf) {
  const int m = blockIdx.x;
  const int t = threadIdx.x;
  __shared__ float sx[2048];
  __shared__ float red[256];
  __shared__ float z1[16];
  const float* xr = x + (long)m * 2048;
  *(float4*)(sx + t * 8)     = *(const float4*)(xr + t * 8);
  *(float4*)(sx + t * 8 + 4) = *(const float4*)(xr + t * 8 + 4);
  __syncthreads();
  const int j = t & 15, seg = t >> 4;
  float s = 0.f;
  for (int d = 0; d < 128; ++d)
    s += sx[seg * 128 + d] * Wgk1[(seg * 128 + d) * 16 + j];
  red[t] = s;
  __syncthreads();
  if (t < 16) {
    float z = 0.f;
    for (int sg = 0; sg < 16; ++sg) z += red[sg * 16 + t];
    z1[t] = z;
  }
  __syncthreads();
#pragma unroll
  for (int r = 0; r < 4; ++r) {
    int n = r * 256 + t;
    float a = bgk2[n];
#pragma unroll
    for (int l2 = 0; l2 < 16; ++l2) a += z1[l2] * Wgk2[l2 * 1024 + n];
    float ls = fminf(a, 0.f) - log1pf(__expf(-fabsf(a)));  // logsigmoid
    gbuf[(long)m * 1024 + n] = f2bf(ls * 0.0625f);
  }
}

// ---------------- Phase A: per-chunk state contribution ----------------
__global__ __launch_bounds__(256) void chunk_contrib_kernel(
    const ushort* __restrict__ qkvg, const ushort* __restrict__ gbuf,
    float* __restrict__ Sall, float* __restrict__ Gtot) {
  const int blk = blockIdx.x;           // 2048 = bh*32 + c
  const int bh = blk >> 5, c = blk & 31;
  const int b = bh >> 4, h = bh & 15;
  const long row0 = (long)b * 2048 + c * 64;
  const int th = threadIdx.x;

  __shared__ float  gc[64][65];
  __shared__ ushort khT[64][72];
  __shared__ ushort vT[128][72];

  {
    const int t = th >> 2;
    const int k0 = (th & 3) * 16;
    const ushort* gp = gbuf + (row0 + t) * 1024 + h * 64 + k0;
    uint4 a = *(const uint4*)gp;
    uint4 b4 = *(const uint4*)(gp + 8);
    float f[8];
    unpack8(a, f);
#pragma unroll
    for (int j = 0; j < 8; ++j) gc[t][k0 + j] = f[j];
    unpack8(b4, f);
#pragma unroll
    for (int j = 0; j < 8; ++j) gc[t][k0 + 8 + j] = f[j];
  }
  __syncthreads();
  if (th < 64) {
    float s = 0.f;
    for (int t = 0; t < 64; ++t) { s += gc[t][th]; gc[t][th] = s; }
  }
  __syncthreads();
  if (th < 64) Gtot[(long)blk * 64 + th] = gc[63][th];

  {
    const int s = th & 63, kq = th >> 6;
    const ushort* kp = qkvg + (row0 + s) * 6144 + 1024 + h * 64 + kq * 16;
    uint4 a = *(const uint4*)kp;
    uint4 b4 = *(const uint4*)(kp + 8);
    float f[16];
    unpack8(a, f); unpack8(b4, f + 8);
#pragma unroll
    for (int j = 0; j < 16; ++j) {
      int k = kq * 16 + j;
      khT[k][s] = f2bf(f[j] * __expf(gc[63][k] - gc[s][k]));
    }
    const ushort* vp = qkvg + (row0 + s) * 6144 + 2048 + h * 128 + kq * 32;
#pragma unroll
    for (int u = 0; u < 4; ++u) {
      uint4 vv = *(const uint4*)(vp + u * 8);
      const ushort* pv = (const ushort*)&vv;
#pragma unroll
      for (int j = 0; j < 8; ++j) vT[kq * 32 + u * 8 + j][s] = pv[j];
    }
  }
  __syncthreads();

  const int w = th >> 6, l = th & 63;
  const int lr = l & 15, kq8 = (l >> 4) * 8;
  f32x4 acc[4][2];
#pragma unroll
  for (int m = 0; m < 4; ++m)
#pragma unroll
    for (int n = 0; n < 2; ++n) acc[m][n] = (f32x4){0.f, 0.f, 0.f, 0.f};
#pragma unroll
  for (int ks = 0; ks < 64; ks += 32) {
#pragma unroll
    for (int m = 0; m < 4; ++m) {
      bf16x8 af = *(const bf16x8*)(&khT[m * 16 + lr][ks + kq8]);
#pragma unroll
      for (int n = 0; n < 2; ++n) {
        bf16x8 bv = *(const bf16x8*)(&vT[w * 32 + n * 16 + lr][ks + kq8]);
        acc[m][n] = __builtin_amdgcn_mfma_f32_16x16x32_bf16(af, bv, acc[m][n], 0, 0, 0);
      }
    }
  }
  float* Cc = Sall + (long)blk * 8192;
  const int rq = (l >> 4) * 4;
#pragma unroll
  for (int m = 0; m < 4; ++m)
#pragma unroll
    for (int n = 0; n < 2; ++n) {
      int k = m * 16 + rq;
      int dv = w * 32 + n * 16 + lr;
#pragma unroll
      for (int r = 0; r < 4; ++r) Cc[(k + r) * 128 + dv] = acc[m][n][r];
    }
}

// ---------------- Phase B: sequential scan over 32 chunks ----------------
__global__ __launch_bounds__(256) void chunk_scan_kernel(
    float* __restrict__ Sall, const float* __restrict__ Gtot) {
  const int blk = blockIdx.x;
  const int bh = blk >> 2, qd = blk & 3;
  const int th = threadIdx.x;
  const int k = th >> 2;
  const int dv = qd * 32 + (th & 3) * 8;
  float* base = Sall + (long)bh * 32 * 8192 + k * 128 + dv;
  const float* gt = Gtot + (long)bh * 32 * 64 + k;
  float S[8];
#pragma unroll
  for (int i = 0; i < 8; ++i) S[i] = 0.f;
  for (int c = 0; c < 32; ++c) {
    float4 c0 = *(const float4*)(base);
    float4 c1 = *(const float4*)(base + 4);
    float eg = __expf(gt[c * 64]);
    float4 s0 = {S[0], S[1], S[2], S[3]};
    float4 s1 = {S[4], S[5], S[6], S[7]};
    *(float4*)(base) = s0;
    *(float4*)(base + 4) = s1;
    S[0] = S[0] * eg + c0.x; S[1] = S[1] * eg + c0.y;
    S[2] = S[2] * eg + c0.z; S[3] = S[3] * eg + c0.w;
    S[4] = S[4] * eg + c1.x; S[5] = S[5] * eg + c1.y;
    S[6] = S[6] * eg + c1.z; S[7] = S[7] * eg + c1.w;
    base += 8192;
  }
}

// ---------------- Phase C: chunk output + fused RMSNorm*swish gate ----------------
__global__ __launch_bounds__(256) void chunk_output_kernel(
    const ushort* __restrict__ qkvg, const ushort* __restrict__ gbuf,
    const float* __restrict__ Sall, const float* __restrict__ norm_w,
    ushort* __restrict__ oo) {
  const int blk = blockIdx.x;
  const int bh = blk >> 5, c = blk & 31;
  const int b = bh >> 4, h = bh & 15;
  const long row0 = (long)b * 2048 + c * 64;
  const int th = threadIdx.x;

  __shared__ float  gc[64][65];
  __shared__ ushort qg[64][72];
  __shared__ ushort kg[64][72];
  __shared__ ushort vT[128][72];
  __shared__ ushort ST[128][72];
  __shared__ ushort P[64][72];
  __shared__ ushort ot[64][136];

  {
    const int t = th >> 2;
    const int s4 = (th & 3);
    const int k0 = s4 * 16;
    const ushort* gp = gbuf + (row0 + t) * 1024 + h * 64 + k0;
    uint4 a = *(const uint4*)gp;
    uint4 b4 = *(const uint4*)(gp + 8);
    float f[8];
    unpack8(a, f);
#pragma unroll
    for (int j = 0; j < 8; ++j) gc[t][k0 + j] = f[j];
    unpack8(b4, f);
#pragma unroll
    for (int j = 0; j < 8; ++j) gc[t][k0 + 8 + j] = f[j];

    const ushort* qp = qkvg + (row0 + t) * 6144 + h * 64 + k0;
    *(uint4*)(&qg[t][k0])     = *(const uint4*)qp;
    *(uint4*)(&qg[t][k0 + 8]) = *(const uint4*)(qp + 8);
    const ushort* kp = qp + 1024;
    *(uint4*)(&kg[t][k0])     = *(const uint4*)kp;
    *(uint4*)(&kg[t][k0 + 8]) = *(const uint4*)(kp + 8);

    const ushort* gtp = qkvg + (row0 + t) * 6144 + 4096 + h * 128 + s4 * 32;
#pragma unroll
    for (int u = 0; u < 4; ++u)
      *(uint4*)(&ot[t][s4 * 32 + u * 8]) = *(const uint4*)(gtp + u * 8);
  }
  {
    const int s = th & 63, kq = th >> 6;
    const ushort* vp = qkvg + (row0 + s) * 6144 + 2048 + h * 128 + kq * 32;
#pragma unroll
    for (int u = 0; u < 4; ++u) {
      uint4 vv = *(const uint4*)(vp + u * 8);
      const ushort* pv = (const ushort*)&vv;
#pragma unroll
      for (int j = 0; j < 8; ++j) vT[kq * 32 + u * 8 + j][s] = pv[j];
    }
  }
  {
    const int k = th >> 2;
    const int dvb = (th & 3) * 32;
    const float* sp = Sall + (long)blk * 8192 + k * 128 + dvb;
#pragma unroll
    for (int u = 0; u < 8; ++u) {
      float4 sv = *(const float4*)(sp + u * 4);
      ST[dvb + u * 4 + 0][k] = f2bf(sv.x);
      ST[dvb + u * 4 + 1][k] = f2bf(sv.y);
      ST[dvb + u * 4 + 2][k] = f2bf(sv.z);
      ST[dvb + u * 4 + 3][k] = f2bf(sv.w);
    }
  }
  __syncthreads();
  if (th < 64) {
    float s = 0.f;
    for (int t = 0; t < 64; ++t) { s += gc[t][th]; gc[t][th] = s; }
  }
  __syncthreads();
  {
    const int t = th & 63, kb = (th >> 6) * 16;
#pragma unroll
    for (int u = 0; u < 2; ++u) {
      uint4 qv = *(const uint4*)(&qg[t][kb + u * 8]);
      uint4 kv = *(const uint4*)(&kg[t][kb + u * 8]);
      float qf[8], kf[8];
      unpack8(qv, qf); unpack8(kv, kf);
      ushort qo[8], ko[8];
#pragma unroll
      for (int j = 0; j < 8; ++j) {
        float g = gc[t][kb + u * 8 + j];
        qo[j] = f2bf(qf[j] * __expf(g) * 0.125f);
        ko[j] = f2bf(kf[j] * __expf(-g));
      }
      *(uint4*)(&qg[t][kb + u * 8]) = *(uint4*)qo;
      *(uint4*)(&kg[t][kb + u * 8]) = *(uint4*)ko;
    }
  }
  __syncthreads();

  const int w = th >> 6, l = th & 63;
  const int lr = l & 15, kq8 = (l >> 4) * 8;
  const int rq = (l >> 4) * 4;

  f32x4 acc1[4];
#pragma unroll
  for (int n = 0; n < 4; ++n) acc1[n] = (f32x4){0.f, 0.f, 0.f, 0.f};
#pragma unroll
  for (int kk = 0; kk < 64; kk += 32) {
    bf16x8 af = *(const bf16x8*)(&qg[w * 16 + lr][kk + kq8]);
#pragma unroll
    for (int n = 0; n < 4; ++n) {
      bf16x8 bv = *(const bf16x8*)(&kg[n * 16 + lr][kk + kq8]);
      acc1[n] = __builtin_amdgcn_mfma_f32_16x16x32_bf16(af, bv, acc1[n], 0, 0, 0);
    }
  }
#pragma unroll
  for (int n = 0; n < 4; ++n) {
    int s = n * 16 + lr;
#pragma unroll
    for (int r = 0; r < 4; ++r) {
      int t = w * 16 + rq + r;
      P[t][s] = f2bf(s <= t ? acc1[n][r] : 0.f);
    }
  }
  __syncthreads();

  f32x4 acc2[8];
#pragma unroll
  for (int n = 0; n < 8; ++n) acc2[n] = (f32x4){0.f, 0.f, 0.f, 0.f};
#pragma unroll
  for (int ks = 0; ks < 64; ks += 32) {
    bf16x8 af = *(const bf16x8*)(&P[w * 16 + lr][ks + kq8]);
#pragma unroll
    for (int n = 0; n < 8; ++n) {
      bf16x8 bv = *(const bf16x8*)(&vT[n * 16 + lr][ks + kq8]);
      acc2[n] = __builtin_amdgcn_mfma_f32_16x16x32_bf16(af, bv, acc2[n], 0, 0, 0);
    }
  }
#pragma unroll
  for (int kk = 0; kk < 64; kk += 32) {
    bf16x8 af = *(const bf16x8*)(&qg[w * 16 + lr][kk + kq8]);
#pragma unroll
    for (int n = 0; n < 8; ++n) {
      bf16x8 bv = *(const bf16x8*)(&ST[n * 16 + lr][kk + kq8]);
      acc2[n] = __builtin_amdgcn_mfma_f32_16x16x32_bf16(af, bv, acc2[n], 0, 0, 0);
    }
  }

  float sumsq[4] = {0.f, 0.f, 0.f, 0.f};
#pragma unroll
  for (int n = 0; n < 8; ++n)
#pragma unroll
    for (int r = 0; r < 4; ++r) sumsq[r] += acc2[n][r] * acc2[n][r];
#pragma unroll
  for (int d = 1; d < 16; d <<= 1)
#pragma unroll
    for (int r = 0; r < 4; ++r) sumsq[r] += __shfl_xor(sumsq[r], d);
  float inv[4];
#pragma unroll
  for (int r = 0; r < 4; ++r) inv[r] = rsqrtf(sumsq[r] * (1.f / 128.f) + 1e-5f);

#pragma unroll
  for (int n = 0; n < 8; ++n) {
    int dv = n * 16 + lr;
    float nw = norm_w[dv];
#pragma unroll
    for (int r = 0; r < 4; ++r) {
      int t = w * 16 + rq + r;
      float g = bf2f(ot[t][dv]);
      float sw = g / (1.f + __expf(-g));
      ot[t][dv] = f2bf(acc2[n][r] * inv[r] * nw * sw);
    }
  }
  __syncthreads();

  {
    const int row = th >> 2;
    const int col0 = (th & 3) * 32;
    ushort* op = oo + (row0 + row) * 2048 + h * 128 + col0;
#pragma unroll
    for (int u = 0; u < 4; ++u)
      *(uint4*)(op + u * 8) = *(const uint4*)(&ot[row][col0 + u * 8]);
  }
}

extern "C" void kernel_launch(void* const* d_in, const int* in_sizes, int n_in,
                              void* d_out, int out_size, void* d_ws, size_t ws_size,
                              hipStream_t stream) {
  const float* x      = (const float*)d_in[0];
  const float* Wq     = (const float*)d_in[1];
  const float* Wk     = (const float*)d_in[2];
  const float* Wv     = (const float*)d_in[3];
  const float* Wg     = (const float*)d_in[4];
  const float* Wgk1   = (const float*)d_in[5];
  const float* Wgk2   = (const float*)d_in[6];
  const float* bgk2   = (const float*)d_in[7];
  const float* norm_w = (const float*)d_in[8];
  const float* Wo     = (const float*)d_in[9];
  float* out = (float*)d_out;

  char* ws = (char*)d_ws;
  ushort* WT   = (ushort*)(ws);                        // [6144][2048] bf16  25,165,824
  ushort* WoT  = (ushort*)(ws + 25165824);             // [2048][2048] bf16   8,388,608
  ushort* qkvg = (ushort*)(ws + 33554432);             // [8192][6144] bf16 100,663,296
  ushort* gbuf = (ushort*)(ws + 134217728);            // [8192][1024] bf16  16,777,216
  float*  Sall = (float*)(ws + 150994944);             // [2048][64][128] f32 67,108,864
  ushort* xb   = (ushort*)(ws + 150994944);            // overlay: dead after gemm1
  float*  Gtot = (float*)(ws + 218103808);             // [2048][64] f32        524,288
  ushort* oo   = (ushort*)(ws + 218628096);            // [8192][2048] bf16  33,554,432

  dim3 blk(256);
  f32_to_bf16<<<dim3(8192), blk, 0, stream>>>(x, xb, (long)8192 * 2048);
  transpose_f32_bf16<<<dim3(16, 32), blk, 0, stream>>>(Wq, WT, 2048, 1024);
  transpose_f32_bf16<<<dim3(16, 32), blk, 0, stream>>>(Wk, WT + (size_t)1024 * 2048, 2048, 1024);
  transpose_f32_bf16<<<dim3(32, 32), blk, 0, stream>>>(Wv, WT + (size_t)2048 * 2048, 2048, 2048);
  transpose_f32_bf16<<<dim3(32, 32), blk, 0, stream>>>(Wg, WT + (size_t)4096 * 2048, 2048, 2048);
  transpose_f32_bf16<<<dim3(32, 32), blk, 0, stream>>>(Wo, WoT, 2048, 2048);

  gemm_bt8<ushort><<<dim3(768), dim3(512), 0, stream>>>(xb, WT, qkvg, 8192, 6144, 2048);
  gate_kernel<<<dim3(8192), blk, 0, stream>>>(x, Wgk1, Wgk2, bgk2, gbuf);

  chunk_contrib_kernel<<<dim3(2048), blk, 0, stream>>>(qkvg, gbuf, Sall, Gtot);
  chunk_scan_kernel<<<dim3(256), blk, 0, stream>>>(Sall, Gtot);
  chunk_output_kernel<<<dim3(2048), blk, 0, stream>>>(qkvg, gbuf, Sall, norm_w, oo);

  gemm_bt8<float><<<dim3(256), dim3(512), 0, stream>>>(oo, WoT, out, 8192, 2048, 2048);
}

// Round 5
// 523.745 us; speedup vs baseline: 2.8071x; 1.0043x over previous
//
#include <hip/hip_runtime.h>
#include <hip/hip_bf16.h>
#include <type_traits>

// GLA attention forward: B=4,T=2048,D=2048,H=16,DK=64,DV=128,LR=16
// Inputs/outputs are float32. bf16 internally for MFMA.
// Chunked GLA (chunk=64) + 256^2 8-phase GEMM (T1+T2(3-bit)+T3/T4+T5).

using bf16x8 = __attribute__((ext_vector_type(8))) short;
using f32x4  = __attribute__((ext_vector_type(4))) float;

static __device__ __forceinline__ float bf2f(ushort u) {
  union { unsigned int i; float f; } v;
  v.i = ((unsigned int)u) << 16;
  return v.f;
}
static __device__ __forceinline__ ushort f2bf(float f) {
  __hip_bfloat16 h = __float2bfloat16(f);
  return *reinterpret_cast<ushort*>(&h);
}
static __device__ __forceinline__ unsigned int pack2(float lo, float hi) {
  return (unsigned int)f2bf(lo) | ((unsigned int)f2bf(hi) << 16);
}
static __device__ __forceinline__ void unpack8(uint4 v, float* f) {
  f[0] = bf2f((ushort)(v.x & 0xffff)); f[1] = bf2f((ushort)(v.x >> 16));
  f[2] = bf2f((ushort)(v.y & 0xffff)); f[3] = bf2f((ushort)(v.y >> 16));
  f[4] = bf2f((ushort)(v.z & 0xffff)); f[5] = bf2f((ushort)(v.z >> 16));
  f[6] = bf2f((ushort)(v.w & 0xffff)); f[7] = bf2f((ushort)(v.w >> 16));
}

#define GLDS16(g, l) __builtin_amdgcn_global_load_lds( \
    (const __attribute__((address_space(1))) unsigned int*)(g), \
    (__attribute__((address_space(3))) unsigned int*)(l), 16, 0, 0)

// 3-bit LDS column-slot swizzle (slot = 16B unit within a 128B row of [.][64] bf16)
#define SWZ3(row) ((((row) & 1) << 2) | (((row) >> 1) & 3))

// ---------------- f32 -> bf16 elementwise ----------------
__global__ __launch_bounds__(256) void f32_to_bf16(
    const float* __restrict__ in, ushort* __restrict__ out, long n) {
  long i = ((long)blockIdx.x * 256 + threadIdx.x) * 8;
  if (i >= n) return;
  float4 a = *(const float4*)(in + i);
  float4 b = *(const float4*)(in + i + 4);
  uint4 o;
  o.x = pack2(a.x, a.y); o.y = pack2(a.z, a.w);
  o.z = pack2(b.x, b.y); o.w = pack2(b.z, b.w);
  *(uint4*)(out + i) = o;
}

// ---------------- transpose f32 in[R][C] -> bf16 out[C][R] ----------------
__global__ __launch_bounds__(256) void transpose_f32_bf16(
    const float* __restrict__ in, ushort* __restrict__ out, int R, int C) {
  __shared__ float tile[64][65];
  const int t = threadIdx.x;
  const int tc = blockIdx.x * 64;
  const int tr = blockIdx.y * 64;
  const int lr = t >> 2;
  const int lc = (t & 3) * 16;
  const float* ip = in + (long)(tr + lr) * C + tc + lc;
#pragma unroll
  for (int j = 0; j < 4; ++j)
    *(float4*)(&tile[lr][lc + j * 4]) = *(const float4*)(ip + j * 4);
  __syncthreads();
  const int c = t >> 2;
  const int r0 = (t & 3) * 16;
  ushort tmp[16];
#pragma unroll
  for (int j = 0; j < 16; ++j) tmp[j] = f2bf(tile[r0 + j][c]);
  ushort* op = out + (long)(tc + c) * R + tr + r0;
  *(uint4*)(op)     = *(uint4*)(tmp);
  *(uint4*)(op + 8) = *(uint4*)(tmp + 8);
}

// ---------------- 256x256 8-phase GEMM: C[M][N] = A[M][K] * BT[N][K]^T ----------------
// BM=BN=256, BK=64, 512 thr = 8 waves (2m x 4n). Phase (mh,nh) touches A-half mh, B-half nh.
// LDS 128 KiB: A,B each 2buf x [256][64] bf16. 3-bit slot swizzle SWZ3(row): linear
// global_load_lds dest + inverse-permuted global source + same XOR on ds_read (rule #21).
// Staging order per K-tile: A.h0,B.h0,B.h1,A.h1; phase p stages {kt+1.Ah1, kt+2.Ah0,
// kt+2.Bh0, kt+2.Bh1}; boundary s_waitcnt vmcnt(6) forces kt+1 complete (never 0 mid-loop).
template <typename OT>
__global__ __launch_bounds__(512, 2) void gemm_bt8(
    const ushort* __restrict__ A, const ushort* __restrict__ BT,
    OT* __restrict__ C, int M, int N, int K) {
  __shared__ ushort sA[2 * 16384];
  __shared__ ushort sB[2 * 16384];
  const int t = threadIdx.x;
  const int nbx = N >> 8;
  // XCD-aware swizzle (gridDim.x % 8 == 0)
  const int cpx = gridDim.x >> 3;
  const int wg = ((int)blockIdx.x & 7) * cpx + ((int)blockIdx.x >> 3);
  const int brow = (wg / nbx) * 256;
  const int bcol = (wg % nbx) * 256;

  const int w = t >> 6, l = t & 63;
  const int wm = w >> 2, wn = w & 3;
  const int lr = l & 15, lk = l >> 4;
  const int NT = K >> 6;

  // staging: thread t fills physical slot (t&7) of row (t>>3); its global source is the
  // logical slot (t&7)^SWZ3(row) so that swizzled ds_reads see linear data.
  const int srow = t >> 3;
  const int cswz = ((t & 7) ^ SWZ3(srow)) * 8;
  const ushort* Abase = A + (size_t)(brow + srow) * K + cswz;
  const ushort* Bbase = BT + (size_t)(bcol + srow) * K + cswz;
  const int t8 = t * 8;

  auto stageA = [&](int bb, int hh, int jt) {
    const ushort* s = Abase + (size_t)(hh * 128) * K + jt * 64;
    ushort* d = sA + bb * 16384 + hh * 8192 + t8;
    GLDS16(s, d);
    GLDS16(s + (size_t)64 * K, d + 4096);   // rows 64..127: SWZ3 period-8 -> same cswz
  };
  auto stageB = [&](int bb, int hh, int jt) {
    const ushort* s = Bbase + (size_t)(hh * 128) * K + jt * 64;
    ushort* d = sB + bb * 16384 + hh * 8192 + t8;
    GLDS16(s, d);
    GLDS16(s + (size_t)64 * K, d + 4096);
  };

  // ds_read offsets (swizzled): fragment row = (w*16+lr), slots lk / 4+lk XOR SWZ3(row)
  const int swz = SWZ3(lr);
  const int ks0 = ((0 + lk) ^ swz) * 8;
  const int ks1 = ((4 + lk) ^ swz) * 8;
  const int aRd = (wm * 16 + lr) * 64;
  const int bRd = (wn * 16 + lr) * 64;

  f32x4 acc[8][4];
#pragma unroll
  for (int m = 0; m < 8; ++m)
#pragma unroll
    for (int n = 0; n < 4; ++n) acc[m][n] = (f32x4){0.f, 0.f, 0.f, 0.f};

  // prologue: K-tile 0 (4 halves) -> vmcnt(4) -> K-tile 1 first 3 halves -> vmcnt(6)
  stageA(0, 0, 0); stageB(0, 0, 0); stageB(0, 1, 0); stageA(0, 1, 0);
  asm volatile("s_waitcnt vmcnt(4)" ::: "memory");
  stageA(1, 0, 1); stageB(1, 0, 1); stageB(1, 1, 1);
  asm volatile("s_waitcnt vmcnt(6)" ::: "memory");
  __builtin_amdgcn_s_barrier();

  for (int kt = 0; kt < NT; ++kt) {
    const int bb = kt & 1;
    const int aOff = bb * 16384, bOff = bb * 16384;
    bf16x8 aF[4][2], bF[2][2][2];

    // ---- phase 0: (mh0, nh0); 12 ds_reads; stage kt+1.A.h1 ----
#pragma unroll
    for (int m = 0; m < 4; ++m) {
      aF[m][0] = *(const bf16x8*)(sA + aOff + aRd + m * 2048 + ks0);
      aF[m][1] = *(const bf16x8*)(sA + aOff + aRd + m * 2048 + ks1);
    }
#pragma unroll
    for (int n = 0; n < 2; ++n) {
      bF[0][n][0] = *(const bf16x8*)(sB + bOff + bRd + n * 4096 + ks0);
      bF[0][n][1] = *(const bf16x8*)(sB + bOff + bRd + n * 4096 + ks1);
    }
    if (kt + 1 < NT) stageA(bb ^ 1, 1, kt + 1);
    __builtin_amdgcn_s_barrier();
    __builtin_amdgcn_s_setprio(1);
#pragma unroll
    for (int m = 0; m < 4; ++m)
#pragma unroll
      for (int n = 0; n < 2; ++n) {
        acc[m][n] = __builtin_amdgcn_mfma_f32_16x16x32_bf16(aF[m][0], bF[0][n][0], acc[m][n], 0, 0, 0);
        acc[m][n] = __builtin_amdgcn_mfma_f32_16x16x32_bf16(aF[m][1], bF[0][n][1], acc[m][n], 0, 0, 0);
      }
    __builtin_amdgcn_s_setprio(0);
    __builtin_amdgcn_s_barrier();

    // ---- phase 1: (mh0, nh1); 4 ds_reads; stage kt+2.A.h0 ----
#pragma unroll
    for (int n = 0; n < 2; ++n) {
      bF[1][n][0] = *(const bf16x8*)(sB + bOff + 8192 + bRd + n * 4096 + ks0);
      bF[1][n][1] = *(const bf16x8*)(sB + bOff + 8192 + bRd + n * 4096 + ks1);
    }
    if (kt + 2 < NT) stageA(bb, 0, kt + 2);
    __builtin_amdgcn_s_barrier();
    __builtin_amdgcn_s_setprio(1);
#pragma unroll
    for (int m = 0; m < 4; ++m)
#pragma unroll
      for (int n = 0; n < 2; ++n) {
        acc[m][2 + n] = __builtin_amdgcn_mfma_f32_16x16x32_bf16(aF[m][0], bF[1][n][0], acc[m][2 + n], 0, 0, 0);
        acc[m][2 + n] = __builtin_amdgcn_mfma_f32_16x16x32_bf16(aF[m][1], bF[1][n][1], acc[m][2 + n], 0, 0, 0);
      }
    __builtin_amdgcn_s_setprio(0);
    __builtin_amdgcn_s_barrier();

    // ---- phase 2: (mh1, nh0); 8 ds_reads; stage kt+2.B.h0 ----
#pragma unroll
    for (int m = 0; m < 4; ++m) {
      aF[m][0] = *(const bf16x8*)(sA + aOff + 8192 + aRd + m * 2048 + ks0);
      aF[m][1] = *(const bf16x8*)(sA + aOff + 8192 + aRd + m * 2048 + ks1);
    }
    if (kt + 2 < NT) stageB(bb, 0, kt + 2);
    __builtin_amdgcn_s_barrier();
    __builtin_amdgcn_s_setprio(1);
#pragma unroll
    for (int m = 0; m < 4; ++m)
#pragma unroll
      for (int n = 0; n < 2; ++n) {
        acc[4 + m][n] = __builtin_amdgcn_mfma_f32_16x16x32_bf16(aF[m][0], bF[0][n][0], acc[4 + m][n], 0, 0, 0);
        acc[4 + m][n] = __builtin_amdgcn_mfma_f32_16x16x32_bf16(aF[m][1], bF[0][n][1], acc[4 + m][n], 0, 0, 0);
      }
    __builtin_amdgcn_s_setprio(0);
    __builtin_amdgcn_s_barrier();

    // ---- phase 3: (mh1, nh1); 0 ds_reads; stage kt+2.B.h1; boundary vmcnt ----
    if (kt + 2 < NT) stageB(bb, 1, kt + 2);
    __builtin_amdgcn_s_barrier();
    __builtin_amdgcn_s_setprio(1);
#pragma unroll
    for (int m = 0; m < 4; ++m)
#pragma unroll
      for (int n = 0; n < 2; ++n) {
        acc[4 + m][2 + n] = __builtin_amdgcn_mfma_f32_16x16x32_bf16(aF[m][0], bF[1][n][0], acc[4 + m][2 + n], 0, 0, 0);
        acc[4 + m][2 + n] = __builtin_amdgcn_mfma_f32_16x16x32_bf16(aF[m][1], bF[1][n][1], acc[4 + m][2 + n], 0, 0, 0);
      }
    __builtin_amdgcn_s_setprio(0);
    if (kt < NT - 2)       asm volatile("s_waitcnt vmcnt(6)" ::: "memory");
    else if (kt == NT - 2) asm volatile("s_waitcnt vmcnt(0)" ::: "memory");
    __builtin_amdgcn_s_barrier();
  }

  // epilogue: C/D layout col=lane&15, row=(lane>>4)*4+reg
  const int rq = lk * 4;
#pragma unroll
  for (int mq = 0; mq < 8; ++mq)
#pragma unroll
    for (int nq = 0; nq < 4; ++nq) {
      long row = brow + mq * 32 + wm * 16 + rq;
      long col = bcol + nq * 64 + wn * 16 + lr;
      OT* cp = C + row * N + col;
#pragma unroll
      for (int r = 0; r < 4; ++r) {
        if constexpr (std::is_same_v<OT, ushort>) cp[(long)r * N] = f2bf(acc[mq][nq][r]);
        else                                      cp[(long)r * N] = acc[mq][nq][r];
      }
    }
}

// ---------------- gate path: gbuf[m][1024] = bf16( logsigmoid((x@Wgk1)@Wgk2+b)/16 ) ----------------
__global__ __launch_bounds__(256) void gate_kernel(
    const float* __restrict__ x, const float* __restrict__ Wgk1,
    const float* __restrict__ Wgk2, const float* __restrict__ bgk2,
    ushort* __restrict__ gbuf) {
  const int m = blockIdx.x;
  const int t = threadIdx.x;
  __shared__ float sx[2048];
  __shared__ float red[256];
  __shared__ float z1[16];
  const float* xr = x + (long)m * 2048;
  *(float4*)(sx + t * 8)     = *(const float4*)(xr + t * 8);
  *(float4*)(sx + t * 8 + 4) = *(const float4*)(xr + t * 8 + 4);
  __syncthreads();
  const int j = t & 15, seg = t >> 4;
  float s = 0.f;
  for (int d = 0; d < 128; ++d)
    s += sx[seg * 128 + d] * Wgk1[(seg * 128 + d) * 16 + j];
  red[t] = s;
  __syncthreads();
  if (t < 16) {
    float z = 0.f;
    for (int sg = 0; sg < 16; ++sg) z += red[sg * 16 + t];
    z1[t] = z;
  }
  __syncthreads();
#pragma unroll
  for (int r = 0; r < 4; ++r) {
    int n = r * 256 + t;
    float a = bgk2[n];
#pragma unroll
    for (int l2 = 0; l2 < 16; ++l2) a += z1[l2] * Wgk2[l2 * 1024 + n];
    float ls = fminf(a, 0.f) - log1pf(__expf(-fabsf(a)));  // logsigmoid
    gbuf[(long)m * 1024 + n] = f2bf(ls * 0.0625f);
  }
}

// ---------------- Phase A: per-chunk state contribution ----------------
__global__ __launch_bounds__(256) void chunk_contrib_kernel(
    const ushort* __restrict__ qkvg, const ushort* __restrict__ gbuf,
    float* __restrict__ Sall, float* __restrict__ Gtot) {
  const int blk = blockIdx.x;           // 2048 = bh*32 + c
  const int bh = blk >> 5, c = blk & 31;
  const int b = bh >> 4, h = bh & 15;
  const long row0 = (long)b * 2048 + c * 64;
  const int th = threadIdx.x;

  __shared__ float  gc[64][65];
  __shared__ ushort khT[64][72];
  __shared__ ushort vT[128][72];

  {
    const int t = th >> 2;
    const int k0 = (th & 3) * 16;
    const ushort* gp = gbuf + (row0 + t) * 1024 + h * 64 + k0;
    uint4 a = *(const uint4*)gp;
    uint4 b4 = *(const uint4*)(gp + 8);
    float f[8];
    unpack8(a, f);
#pragma unroll
    for (int j = 0; j < 8; ++j) gc[t][k0 + j] = f[j];
    unpack8(b4, f);
#pragma unroll
    for (int j = 0; j < 8; ++j) gc[t][k0 + 8 + j] = f[j];
  }
  __syncthreads();
  if (th < 64) {
    float s = 0.f;
    for (int t = 0; t < 64; ++t) { s += gc[t][th]; gc[t][th] = s; }
  }
  __syncthreads();
  if (th < 64) Gtot[(long)blk * 64 + th] = gc[63][th];

  {
    const int s = th & 63, kq = th >> 6;
    const ushort* kp = qkvg + (row0 + s) * 6144 + 1024 + h * 64 + kq * 16;
    uint4 a = *(const uint4*)kp;
    uint4 b4 = *(const uint4*)(kp + 8);
    float f[16];
    unpack8(a, f); unpack8(b4, f + 8);
#pragma unroll
    for (int j = 0; j < 16; ++j) {
      int k = kq * 16 + j;
      khT[k][s] = f2bf(f[j] * __expf(gc[63][k] - gc[s][k]));
    }
    const ushort* vp = qkvg + (row0 + s) * 6144 + 2048 + h * 128 + kq * 32;
#pragma unroll
    for (int u = 0; u < 4; ++u) {
      uint4 vv = *(const uint4*)(vp + u * 8);
      const ushort* pv = (const ushort*)&vv;
#pragma unroll
      for (int j = 0; j < 8; ++j) vT[kq * 32 + u * 8 + j][s] = pv[j];
    }
  }
  __syncthreads();

  const int w = th >> 6, l = th & 63;
  const int lr = l & 15, kq8 = (l >> 4) * 8;
  f32x4 acc[4][2];
#pragma unroll
  for (int m = 0; m < 4; ++m)
#pragma unroll
    for (int n = 0; n < 2; ++n) acc[m][n] = (f32x4){0.f, 0.f, 0.f, 0.f};
#pragma unroll
  for (int ks = 0; ks < 64; ks += 32) {
#pragma unroll
    for (int m = 0; m < 4; ++m) {
      bf16x8 af = *(const bf16x8*)(&khT[m * 16 + lr][ks + kq8]);
#pragma unroll
      for (int n = 0; n < 2; ++n) {
        bf16x8 bv = *(const bf16x8*)(&vT[w * 32 + n * 16 + lr][ks + kq8]);
        acc[m][n] = __builtin_amdgcn_mfma_f32_16x16x32_bf16(af, bv, acc[m][n], 0, 0, 0);
      }
    }
  }
  float* Cc = Sall + (long)blk * 8192;
  const int rq = (l >> 4) * 4;
#pragma unroll
  for (int m = 0; m < 4; ++m)
#pragma unroll
    for (int n = 0; n < 2; ++n) {
      int k = m * 16 + rq;
      int dv = w * 32 + n * 16 + lr;
#pragma unroll
      for (int r = 0; r < 4; ++r) Cc[(k + r) * 128 + dv] = acc[m][n][r];
    }
}

// ---------------- Phase B: sequential scan over 32 chunks ----------------
__global__ __launch_bounds__(256) void chunk_scan_kernel(
    float* __restrict__ Sall, const float* __restrict__ Gtot) {
  const int blk = blockIdx.x;
  const int bh = blk >> 2, qd = blk & 3;
  const int th = threadIdx.x;
  const int k = th >> 2;
  const int dv = qd * 32 + (th & 3) * 8;
  float* base = Sall + (long)bh * 32 * 8192 + k * 128 + dv;
  const float* gt = Gtot + (long)bh * 32 * 64 + k;
  float S[8];
#pragma unroll
  for (int i = 0; i < 8; ++i) S[i] = 0.f;
  for (int c = 0; c < 32; ++c) {
    float4 c0 = *(const float4*)(base);
    float4 c1 = *(const float4*)(base + 4);
    float eg = __expf(gt[c * 64]);
    float4 s0 = {S[0], S[1], S[2], S[3]};
    float4 s1 = {S[4], S[5], S[6], S[7]};
    *(float4*)(base) = s0;
    *(float4*)(base + 4) = s1;
    S[0] = S[0] * eg + c0.x; S[1] = S[1] * eg + c0.y;
    S[2] = S[2] * eg + c0.z; S[3] = S[3] * eg + c0.w;
    S[4] = S[4] * eg + c1.x; S[5] = S[5] * eg + c1.y;
    S[6] = S[6] * eg + c1.z; S[7] = S[7] * eg + c1.w;
    base += 8192;
  }
}

// ---------------- Phase C: chunk output + fused RMSNorm*swish gate ----------------
__global__ __launch_bounds__(256) void chunk_output_kernel(
    const ushort* __restrict__ qkvg, const ushort* __restrict__ gbuf,
    const float* __restrict__ Sall, const float* __restrict__ norm_w,
    ushort* __restrict__ oo) {
  const int blk = blockIdx.x;
  const int bh = blk >> 5, c = blk & 31;
  const int b = bh >> 4, h = bh & 15;
  const long row0 = (long)b * 2048 + c * 64;
  const int th = threadIdx.x;

  __shared__ float  gc[64][65];
  __shared__ ushort qg[64][72];
  __shared__ ushort kg[64][72];
  __shared__ ushort vT[128][72];
  __shared__ ushort ST[128][72];
  __shared__ ushort P[64][72];
  __shared__ ushort ot[64][136];

  {
    const int t = th >> 2;
    const int s4 = (th & 3);
    const int k0 = s4 * 16;
    const ushort* gp = gbuf + (row0 + t) * 1024 + h * 64 + k0;
    uint4 a = *(const uint4*)gp;
    uint4 b4 = *(const uint4*)(gp + 8);
    float f[8];
    unpack8(a, f);
#pragma unroll
    for (int j = 0; j < 8; ++j) gc[t][k0 + j] = f[j];
    unpack8(b4, f);
#pragma unroll
    for (int j = 0; j < 8; ++j) gc[t][k0 + 8 + j] = f[j];

    const ushort* qp = qkvg + (row0 + t) * 6144 + h * 64 + k0;
    *(uint4*)(&qg[t][k0])     = *(const uint4*)qp;
    *(uint4*)(&qg[t][k0 + 8]) = *(const uint4*)(qp + 8);
    const ushort* kp = qp + 1024;
    *(uint4*)(&kg[t][k0])     = *(const uint4*)kp;
    *(uint4*)(&kg[t][k0 + 8]) = *(const uint4*)(kp + 8);

    const ushort* gtp = qkvg + (row0 + t) * 6144 + 4096 + h * 128 + s4 * 32;
#pragma unroll
    for (int u = 0; u < 4; ++u)
      *(uint4*)(&ot[t][s4 * 32 + u * 8]) = *(const uint4*)(gtp + u * 8);
  }
  {
    const int s = th & 63, kq = th >> 6;
    const ushort* vp = qkvg + (row0 + s) * 6144 + 2048 + h * 128 + kq * 32;
#pragma unroll
    for (int u = 0; u < 4; ++u) {
      uint4 vv = *(const uint4*)(vp + u * 8);
      const ushort* pv = (const ushort*)&vv;
#pragma unroll
      for (int j = 0; j < 8; ++j) vT[kq * 32 + u * 8 + j][s] = pv[j];
    }
  }
  {
    const int k = th >> 2;
    const int dvb = (th & 3) * 32;
    const float* sp = Sall + (long)blk * 8192 + k * 128 + dvb;
#pragma unroll
    for (int u = 0; u < 8; ++u) {
      float4 sv = *(const float4*)(sp + u * 4);
      ST[dvb + u * 4 + 0][k] = f2bf(sv.x);
      ST[dvb + u * 4 + 1][k] = f2bf(sv.y);
      ST[dvb + u * 4 + 2][k] = f2bf(sv.z);
      ST[dvb + u * 4 + 3][k] = f2bf(sv.w);
    }
  }
  __syncthreads();
  if (th < 64) {
    float s = 0.f;
    for (int t = 0; t < 64; ++t) { s += gc[t][th]; gc[t][th] = s; }
  }
  __syncthreads();
  {
    const int t = th & 63, kb = (th >> 6) * 16;
#pragma unroll
    for (int u = 0; u < 2; ++u) {
      uint4 qv = *(const uint4*)(&qg[t][kb + u * 8]);
      uint4 kv = *(const uint4*)(&kg[t][kb + u * 8]);
      float qf[8], kf[8];
      unpack8(qv, qf); unpack8(kv, kf);
      ushort qo[8], ko[8];
#pragma unroll
      for (int j = 0; j < 8; ++j) {
        float g = gc[t][kb + u * 8 + j];
        qo[j] = f2bf(qf[j] * __expf(g) * 0.125f);
        ko[j] = f2bf(kf[j] * __expf(-g));
      }
      *(uint4*)(&qg[t][kb + u * 8]) = *(uint4*)qo;
      *(uint4*)(&kg[t][kb + u * 8]) = *(uint4*)ko;
    }
  }
  __syncthreads();

  const int w = th >> 6, l = th & 63;
  const int lr = l & 15, kq8 = (l >> 4) * 8;
  const int rq = (l >> 4) * 4;

  f32x4 acc1[4];
#pragma unroll
  for (int n = 0; n < 4; ++n) acc1[n] = (f32x4){0.f, 0.f, 0.f, 0.f};
#pragma unroll
  for (int kk = 0; kk < 64; kk += 32) {
    bf16x8 af = *(const bf16x8*)(&qg[w * 16 + lr][kk + kq8]);
#pragma unroll
    for (int n = 0; n < 4; ++n) {
      bf16x8 bv = *(const bf16x8*)(&kg[n * 16 + lr][kk + kq8]);
      acc1[n] = __builtin_amdgcn_mfma_f32_16x16x32_bf16(af, bv, acc1[n], 0, 0, 0);
    }
  }
#pragma unroll
  for (int n = 0; n < 4; ++n) {
    int s = n * 16 + lr;
#pragma unroll
    for (int r = 0; r < 4; ++r) {
      int t = w * 16 + rq + r;
      P[t][s] = f2bf(s <= t ? acc1[n][r] : 0.f);
    }
  }
  __syncthreads();

  f32x4 acc2[8];
#pragma unroll
  for (int n = 0; n < 8; ++n) acc2[n] = (f32x4){0.f, 0.f, 0.f, 0.f};
#pragma unroll
  for (int ks = 0; ks < 64; ks += 32) {
    bf16x8 af = *(const bf16x8*)(&P[w * 16 + lr][ks + kq8]);
#pragma unroll
    for (int n = 0; n < 8; ++n) {
      bf16x8 bv = *(const bf16x8*)(&vT[n * 16 + lr][ks + kq8]);
      acc2[n] = __builtin_amdgcn_mfma_f32_16x16x32_bf16(af, bv, acc2[n], 0, 0, 0);
    }
  }
#pragma unroll
  for (int kk = 0; kk < 64; kk += 32) {
    bf16x8 af = *(const bf16x8*)(&qg[w * 16 + lr][kk + kq8]);
#pragma unroll
    for (int n = 0; n < 8; ++n) {
      bf16x8 bv = *(const bf16x8*)(&ST[n * 16 + lr][kk + kq8]);
      acc2[n] = __builtin_amdgcn_mfma_f32_16x16x32_bf16(af, bv, acc2[n], 0, 0, 0);
    }
  }

  float sumsq[4] = {0.f, 0.f, 0.f, 0.f};
#pragma unroll
  for (int n = 0; n < 8; ++n)
#pragma unroll
    for (int r = 0; r < 4; ++r) sumsq[r] += acc2[n][r] * acc2[n][r];
#pragma unroll
  for (int d = 1; d < 16; d <<= 1)
#pragma unroll
    for (int r = 0; r < 4; ++r) sumsq[r] += __shfl_xor(sumsq[r], d);
  float inv[4];
#pragma unroll
  for (int r = 0; r < 4; ++r) inv[r] = rsqrtf(sumsq[r] * (1.f / 128.f) + 1e-5f);

#pragma unroll
  for (int n = 0; n < 8; ++n) {
    int dv = n * 16 + lr;
    float nw = norm_w[dv];
#pragma unroll
    for (int r = 0; r < 4; ++r) {
      int t = w * 16 + rq + r;
      float g = bf2f(ot[t][dv]);
      float sw = g / (1.f + __expf(-g));
      ot[t][dv] = f2bf(acc2[n][r] * inv[r] * nw * sw);
    }
  }
  __syncthreads();

  {
    const int row = th >> 2;
    const int col0 = (th & 3) * 32;
    ushort* op = oo + (row0 + row) * 2048 + h * 128 + col0;
#pragma unroll
    for (int u = 0; u < 4; ++u)
      *(uint4*)(op + u * 8) = *(const uint4*)(&ot[row][col0 + u * 8]);
  }
}

extern "C" void kernel_launch(void* const* d_in, const int* in_sizes, int n_in,
                              void* d_out, int out_size, void* d_ws, size_t ws_size,
                              hipStream_t stream) {
  const float* x      = (const float*)d_in[0];
  const float* Wq     = (const float*)d_in[1];
  const float* Wk     = (const float*)d_in[2];
  const float* Wv     = (const float*)d_in[3];
  const float* Wg     = (const float*)d_in[4];
  const float* Wgk1   = (const float*)d_in[5];
  const float* Wgk2   = (const float*)d_in[6];
  const float* bgk2   = (const float*)d_in[7];
  const float* norm_w = (const float*)d_in[8];
  const float* Wo     = (const float*)d_in[9];
  float* out = (float*)d_out;

  char* ws = (char*)d_ws;
  ushort* WT   = (ushort*)(ws);                        // [6144][2048] bf16  25,165,824
  ushort* WoT  = (ushort*)(ws + 25165824);             // [2048][2048] bf16   8,388,608
  ushort* qkvg = (ushort*)(ws + 33554432);             // [8192][6144] bf16 100,663,296
  ushort* gbuf = (ushort*)(ws + 134217728);            // [8192][1024] bf16  16,777,216
  float*  Sall = (float*)(ws + 150994944);             // [2048][64][128] f32 67,108,864
  ushort* xb   = (ushort*)(ws + 150994944);            // overlay: dead after gemm1
  float*  Gtot = (float*)(ws + 218103808);             // [2048][64] f32        524,288
  ushort* oo   = (ushort*)(ws + 218628096);            // [8192][2048] bf16  33,554,432

  dim3 blk(256);
  f32_to_bf16<<<dim3(8192), blk, 0, stream>>>(x, xb, (long)8192 * 2048);
  transpose_f32_bf16<<<dim3(16, 32), blk, 0, stream>>>(Wq, WT, 2048, 1024);
  transpose_f32_bf16<<<dim3(16, 32), blk, 0, stream>>>(Wk, WT + (size_t)1024 * 2048, 2048, 1024);
  transpose_f32_bf16<<<dim3(32, 32), blk, 0, stream>>>(Wv, WT + (size_t)2048 * 2048, 2048, 2048);
  transpose_f32_bf16<<<dim3(32, 32), blk, 0, stream>>>(Wg, WT + (size_t)4096 * 2048, 2048, 2048);
  transpose_f32_bf16<<<dim3(32, 32), blk, 0, stream>>>(Wo, WoT, 2048, 2048);

  gemm_bt8<ushort><<<dim3(768), dim3(512), 0, stream>>>(xb, WT, qkvg, 8192, 6144, 2048);
  gate_kernel<<<dim3(8192), blk, 0, stream>>>(x, Wgk1, Wgk2, bgk2, gbuf);

  chunk_contrib_kernel<<<dim3(2048), blk, 0, stream>>>(qkvg, gbuf, Sall, Gtot);
  chunk_scan_kernel<<<dim3(256), blk, 0, stream>>>(Sall, Gtot);
  chunk_output_kernel<<<dim3(2048), blk, 0, stream>>>(qkvg, gbuf, Sall, norm_w, oo);

  gemm_bt8<float><<<dim3(256), dim3(512), 0, stream>>>(oo, WoT, out, 8192, 2048, 2048);
}

// Round 6
// 476.166 us; speedup vs baseline: 3.0876x; 1.0999x over previous
//
#include <hip/hip_runtime.h>
#include <hip/hip_bf16.h>
#include <type_traits>

// GLA attention forward: B=4,T=2048,D=2048,H=16,DK=64,DV=128,LR=16
// Inputs/outputs f32; bf16 internally. Chunked GLA (chunk=64) +
// 256^2 8-phase GEMM with 32x32x16 MFMA.

using bf16x8 = __attribute__((ext_vector_type(8))) short;
using f32x4  = __attribute__((ext_vector_type(4))) float;
using f32x16 = __attribute__((ext_vector_type(16))) float;

static __device__ __forceinline__ float bf2f(ushort u) {
  union { unsigned int i; float f; } v;
  v.i = ((unsigned int)u) << 16;
  return v.f;
}
static __device__ __forceinline__ ushort f2bf(float f) {
  __hip_bfloat16 h = __float2bfloat16(f);
  return *reinterpret_cast<ushort*>(&h);
}
static __device__ __forceinline__ unsigned int pack2(float lo, float hi) {
  return (unsigned int)f2bf(lo) | ((unsigned int)f2bf(hi) << 16);
}
static __device__ __forceinline__ void unpack8(uint4 v, float* f) {
  f[0] = bf2f((ushort)(v.x & 0xffff)); f[1] = bf2f((ushort)(v.x >> 16));
  f[2] = bf2f((ushort)(v.y & 0xffff)); f[3] = bf2f((ushort)(v.y >> 16));
  f[4] = bf2f((ushort)(v.z & 0xffff)); f[5] = bf2f((ushort)(v.z >> 16));
  f[6] = bf2f((ushort)(v.w & 0xffff)); f[7] = bf2f((ushort)(v.w >> 16));
}

#define GLDS16(g, l) __builtin_amdgcn_global_load_lds( \
    (const __attribute__((address_space(1))) unsigned int*)(g), \
    (__attribute__((address_space(3))) unsigned int*)(l), 16, 0, 0)

#define SWZ3(row) ((((row) & 1) << 2) | (((row) >> 1) & 3))

// ---------------- f32 -> bf16 elementwise ----------------
__global__ __launch_bounds__(256) void f32_to_bf16(
    const float* __restrict__ in, ushort* __restrict__ out, long n) {
  long i = ((long)blockIdx.x * 256 + threadIdx.x) * 8;
  if (i >= n) return;
  float4 a = *(const float4*)(in + i);
  float4 b = *(const float4*)(in + i + 4);
  uint4 o;
  o.x = pack2(a.x, a.y); o.y = pack2(a.z, a.w);
  o.z = pack2(b.x, b.y); o.w = pack2(b.z, b.w);
  *(uint4*)(out + i) = o;
}

// ---------------- transpose f32 in[R][C] -> bf16 out[C][R] ----------------
__global__ __launch_bounds__(256) void transpose_f32_bf16(
    const float* __restrict__ in, ushort* __restrict__ out, int R, int C) {
  __shared__ float tile[64][65];
  const int t = threadIdx.x;
  const int tc = blockIdx.x * 64;
  const int tr = blockIdx.y * 64;
  const int lr = t >> 2;
  const int lc = (t & 3) * 16;
  const float* ip = in + (long)(tr + lr) * C + tc + lc;
#pragma unroll
  for (int j = 0; j < 4; ++j)
    *(float4*)(&tile[lr][lc + j * 4]) = *(const float4*)(ip + j * 4);
  __syncthreads();
  const int c = t >> 2;
  const int r0 = (t & 3) * 16;
  ushort tmp[16];
#pragma unroll
  for (int j = 0; j < 16; ++j) tmp[j] = f2bf(tile[r0 + j][c]);
  ushort* op = out + (long)(tc + c) * R + tr + r0;
  *(uint4*)(op)     = *(uint4*)(tmp);
  *(uint4*)(op + 8) = *(uint4*)(tmp + 8);
}

// ---------------- 256x256 8-phase GEMM (32x32x16 MFMA): C = A * BT^T ----------------
// BM=BN=256, BK=64, 512 thr = 8 waves (2m x 4n). Per-wave C: 128 rows x 64 cols
// (4 mf-frags of 32 rows x 2 nf-frags of 32 cols). Phase (mh,nh) = A-half mh, B-half nh.
// Staging/vmcnt schedule identical to round-4 derivation (counted vmcnt(6), never 0 mid-loop).
template <typename OT>
__global__ __launch_bounds__(512, 2) void gemm_bt8(
    const ushort* __restrict__ A, const ushort* __restrict__ BT,
    OT* __restrict__ C, int M, int N, int K) {
  __shared__ ushort sA[2 * 16384];
  __shared__ ushort sB[2 * 16384];
  const int t = threadIdx.x;
  const int nbx = N >> 8;
  const int cpx = gridDim.x >> 3;
  const int wg = ((int)blockIdx.x & 7) * cpx + ((int)blockIdx.x >> 3);
  const int brow = (wg / nbx) * 256;
  const int bcol = (wg % nbx) * 256;

  const int w = t >> 6, l = t & 63;
  const int wm = w >> 2, wn = w & 3;
  const int l31 = l & 31, l5 = l >> 5;
  const int NT = K >> 6;

  // staging: thread t fills physical slot (t&7) of row (t>>3); global source is logical
  // slot (t&7)^SWZ3(row) so swizzled ds_reads see linear data (rule #21).
  const int srow = t >> 3;
  const int cswz = ((t & 7) ^ SWZ3(srow)) * 8;
  const ushort* Abase = A + (size_t)(brow + srow) * K + cswz;
  const ushort* Bbase = BT + (size_t)(bcol + srow) * K + cswz;
  const int t8 = t * 8;

  auto stageA = [&](int bb, int hh, int jt) {
    const ushort* s = Abase + (size_t)(hh * 128) * K + jt * 64;
    ushort* d = sA + bb * 16384 + hh * 8192 + t8;
    GLDS16(s, d);
    GLDS16(s + (size_t)64 * K, d + 4096);
  };
  auto stageB = [&](int bb, int hh, int jt) {
    const ushort* s = Bbase + (size_t)(hh * 128) * K + jt * 64;
    ushort* d = sB + bb * 16384 + hh * 8192 + t8;
    GLDS16(s, d);
    GLDS16(s + (size_t)64 * K, d + 4096);
  };

  // ds_read geometry: A-operand 32x32x16: lane row = l&31, k-slot = kstep*2 + (l>>5)
  const int swz = SWZ3(l31 & 7);
  const int aRow = (wm * 32 + l31) * 64;
  const int bRow = (wn * 32 + l31) * 64;
#define KSL(ks) ((((ks) * 2 + l5) ^ swz) * 8)

  f32x16 acc[4][2];
#pragma unroll
  for (int m = 0; m < 4; ++m)
#pragma unroll
    for (int n = 0; n < 2; ++n)
#pragma unroll
      for (int r = 0; r < 16; ++r) acc[m][n][r] = 0.f;

  // prologue: K-tile 0 (4 halves) -> vmcnt(4) -> K-tile 1 first 3 halves -> vmcnt(6)
  stageA(0, 0, 0); stageB(0, 0, 0); stageB(0, 1, 0); stageA(0, 1, 0);
  asm volatile("s_waitcnt vmcnt(4)" ::: "memory");
  stageA(1, 0, 1); stageB(1, 0, 1); stageB(1, 1, 1);
  asm volatile("s_waitcnt vmcnt(6)" ::: "memory");
  __builtin_amdgcn_s_barrier();

  for (int kt = 0; kt < NT; ++kt) {
    const int bb = kt & 1;
    const int aOff = bb * 16384, bOff = bb * 16384;
    bf16x8 aF[2][4], bF[2][4];

    // ---- phase 0: (mh0, nh0); 12 ds_reads; stage kt+1.A.h1 ----
#pragma unroll
    for (int mf = 0; mf < 2; ++mf)
#pragma unroll
      for (int ks = 0; ks < 4; ++ks)
        aF[mf][ks] = *(const bf16x8*)(sA + aOff + mf * 4096 + aRow + KSL(ks));
#pragma unroll
    for (int ks = 0; ks < 4; ++ks)
      bF[0][ks] = *(const bf16x8*)(sB + bOff + bRow + KSL(ks));
    if (kt + 1 < NT) stageA(bb ^ 1, 1, kt + 1);
    __builtin_amdgcn_s_barrier();
    __builtin_amdgcn_s_setprio(1);
#pragma unroll
    for (int mf = 0; mf < 2; ++mf)
#pragma unroll
      for (int ks = 0; ks < 4; ++ks)
        acc[mf][0] = __builtin_amdgcn_mfma_f32_32x32x16_bf16(aF[mf][ks], bF[0][ks], acc[mf][0], 0, 0, 0);
    __builtin_amdgcn_s_setprio(0);
    __builtin_amdgcn_s_barrier();

    // ---- phase 1: (mh0, nh1); 4 ds_reads; stage kt+2.A.h0 ----
#pragma unroll
    for (int ks = 0; ks < 4; ++ks)
      bF[1][ks] = *(const bf16x8*)(sB + bOff + 8192 + bRow + KSL(ks));
    if (kt + 2 < NT) stageA(bb, 0, kt + 2);
    __builtin_amdgcn_s_barrier();
    __builtin_amdgcn_s_setprio(1);
#pragma unroll
    for (int mf = 0; mf < 2; ++mf)
#pragma unroll
      for (int ks = 0; ks < 4; ++ks)
        acc[mf][1] = __builtin_amdgcn_mfma_f32_32x32x16_bf16(aF[mf][ks], bF[1][ks], acc[mf][1], 0, 0, 0);
    __builtin_amdgcn_s_setprio(0);
    __builtin_amdgcn_s_barrier();

    // ---- phase 2: (mh1, nh0); 8 ds_reads; stage kt+2.B.h0 ----
#pragma unroll
    for (int mf = 0; mf < 2; ++mf)
#pragma unroll
      for (int ks = 0; ks < 4; ++ks)
        aF[mf][ks] = *(const bf16x8*)(sA + aOff + 8192 + mf * 4096 + aRow + KSL(ks));
    if (kt + 2 < NT) stageB(bb, 0, kt + 2);
    __builtin_amdgcn_s_barrier();
    __builtin_amdgcn_s_setprio(1);
#pragma unroll
    for (int mf = 0; mf < 2; ++mf)
#pragma unroll
      for (int ks = 0; ks < 4; ++ks)
        acc[2 + mf][0] = __builtin_amdgcn_mfma_f32_32x32x16_bf16(aF[mf][ks], bF[0][ks], acc[2 + mf][0], 0, 0, 0);
    __builtin_amdgcn_s_setprio(0);
    __builtin_amdgcn_s_barrier();

    // ---- phase 3: (mh1, nh1); 0 ds_reads; stage kt+2.B.h1; boundary vmcnt ----
    if (kt + 2 < NT) stageB(bb, 1, kt + 2);
    __builtin_amdgcn_s_barrier();
    __builtin_amdgcn_s_setprio(1);
#pragma unroll
    for (int mf = 0; mf < 2; ++mf)
#pragma unroll
      for (int ks = 0; ks < 4; ++ks)
        acc[2 + mf][1] = __builtin_amdgcn_mfma_f32_32x32x16_bf16(aF[mf][ks], bF[1][ks], acc[2 + mf][1], 0, 0, 0);
    __builtin_amdgcn_s_setprio(0);
    if (kt < NT - 2)       asm volatile("s_waitcnt vmcnt(6)" ::: "memory");
    else if (kt == NT - 2) asm volatile("s_waitcnt vmcnt(0)" ::: "memory");
    __builtin_amdgcn_s_barrier();
  }
#undef KSL

  // epilogue: 32x32 C/D layout col=lane&31, row=(reg&3)+8*(reg>>2)+4*(lane>>5)
#pragma unroll
  for (int mf = 0; mf < 4; ++mf)
#pragma unroll
    for (int nf = 0; nf < 2; ++nf) {
      long col = bcol + nf * 128 + wn * 32 + l31;
      long rbase = brow + mf * 64 + wm * 32 + 4 * l5;
#pragma unroll
      for (int r = 0; r < 16; ++r) {
        long row = rbase + (r & 3) + 8 * (r >> 2);
        if constexpr (std::is_same_v<OT, ushort>) C[row * N + col] = f2bf(acc[mf][nf][r]);
        else                                      C[row * N + col] = acc[mf][nf][r];
      }
    }
}

// ---------------- gate path (reads bf16 xb): gbuf = bf16(logsigmoid(..)/16) ----------------
__global__ __launch_bounds__(256) void gate_kernel(
    const ushort* __restrict__ xb, const float* __restrict__ Wgk1,
    const float* __restrict__ Wgk2, const float* __restrict__ bgk2,
    ushort* __restrict__ gbuf) {
  const int m = blockIdx.x;
  const int t = threadIdx.x;
  __shared__ float sx[2048];
  __shared__ float red[256];
  __shared__ float z1[16];
  const ushort* xr = xb + (long)m * 2048;
  {
    uint4 v = *(const uint4*)(xr + t * 8);
    float f[8];
    unpack8(v, f);
#pragma unroll
    for (int j = 0; j < 8; ++j) sx[t * 8 + j] = f[j];
  }
  __syncthreads();
  const int j = t & 15, seg = t >> 4;
  float s = 0.f;
  for (int d = 0; d < 128; ++d)
    s += sx[seg * 128 + d] * Wgk1[(seg * 128 + d) * 16 + j];
  red[t] = s;
  __syncthreads();
  if (t < 16) {
    float z = 0.f;
    for (int sg = 0; sg < 16; ++sg) z += red[sg * 16 + t];
    z1[t] = z;
  }
  __syncthreads();
#pragma unroll
  for (int r = 0; r < 4; ++r) {
    int n = r * 256 + t;
    float a = bgk2[n];
#pragma unroll
    for (int l2 = 0; l2 < 16; ++l2) a += z1[l2] * Wgk2[l2 * 1024 + n];
    float ls = fminf(a, 0.f) - log1pf(__expf(-fabsf(a)));  // logsigmoid
    gbuf[(long)m * 1024 + n] = f2bf(ls * 0.0625f);
  }
}

// ---------------- Phase A: per-chunk contribution -> bf16 S^T [128dv][64k] ----------------
__global__ __launch_bounds__(256) void chunk_contrib_kernel(
    const ushort* __restrict__ qkvg, const ushort* __restrict__ gbuf,
    ushort* __restrict__ STbuf, float* __restrict__ EGtot) {
  const int blk = blockIdx.x;           // 2048 = bh*32 + c
  const int bh = blk >> 5, c = blk & 31;
  const int b = bh >> 4, h = bh & 15;
  const long row0 = (long)b * 2048 + c * 64;
  const int th = threadIdx.x;

  __shared__ float  gc[64][65];
  __shared__ ushort khT[64][72];
  __shared__ ushort vT[128][72];

  {
    const int t = th >> 2;
    const int k0 = (th & 3) * 16;
    const ushort* gp = gbuf + (row0 + t) * 1024 + h * 64 + k0;
    uint4 a = *(const uint4*)gp;
    uint4 b4 = *(const uint4*)(gp + 8);
    float f[8];
    unpack8(a, f);
#pragma unroll
    for (int j = 0; j < 8; ++j) gc[t][k0 + j] = f[j];
    unpack8(b4, f);
#pragma unroll
    for (int j = 0; j < 8; ++j) gc[t][k0 + 8 + j] = f[j];
  }
  __syncthreads();
  if (th < 64) {
    float s = 0.f;
    for (int t = 0; t < 64; ++t) { s += gc[t][th]; gc[t][th] = s; }
  }
  __syncthreads();
  if (th < 64) EGtot[(long)blk * 64 + th] = __expf(gc[63][th]);

  {
    const int s = th & 63, kq = th >> 6;
    const ushort* kp = qkvg + (row0 + s) * 6144 + 1024 + h * 64 + kq * 16;
    uint4 a = *(const uint4*)kp;
    uint4 b4 = *(const uint4*)(kp + 8);
    float f[16];
    unpack8(a, f); unpack8(b4, f + 8);
#pragma unroll
    for (int j = 0; j < 16; ++j) {
      int k = kq * 16 + j;
      khT[k][s] = f2bf(f[j] * __expf(gc[63][k] - gc[s][k]));
    }
    const ushort* vp = qkvg + (row0 + s) * 6144 + 2048 + h * 128 + kq * 32;
#pragma unroll
    for (int u = 0; u < 4; ++u) {
      uint4 vv = *(const uint4*)(vp + u * 8);
      const ushort* pv = (const ushort*)&vv;
#pragma unroll
      for (int j = 0; j < 8; ++j) vT[kq * 32 + u * 8 + j][s] = pv[j];
    }
  }
  __syncthreads();

  const int w = th >> 6, l = th & 63;
  const int lr = l & 15, kq8 = (l >> 4) * 8;
  f32x4 acc[4][2];
#pragma unroll
  for (int m = 0; m < 4; ++m)
#pragma unroll
    for (int n = 0; n < 2; ++n) acc[m][n] = (f32x4){0.f, 0.f, 0.f, 0.f};
#pragma unroll
  for (int ks = 0; ks < 64; ks += 32) {
#pragma unroll
    for (int m = 0; m < 4; ++m) {
      bf16x8 af = *(const bf16x8*)(&khT[m * 16 + lr][ks + kq8]);
#pragma unroll
      for (int n = 0; n < 2; ++n) {
        bf16x8 bv = *(const bf16x8*)(&vT[w * 32 + n * 16 + lr][ks + kq8]);
        acc[m][n] = __builtin_amdgcn_mfma_f32_16x16x32_bf16(af, bv, acc[m][n], 0, 0, 0);
      }
    }
  }
  // write transposed bf16: STc[dv][k], k = m*16 + rq + r (4 consecutive -> 8B store)
  ushort* Cc = STbuf + (long)blk * 8192;
  const int rq = (l >> 4) * 4;
#pragma unroll
  for (int m = 0; m < 4; ++m)
#pragma unroll
    for (int n = 0; n < 2; ++n) {
      int dv = w * 32 + n * 16 + lr;
      ushort tmp[4];
#pragma unroll
      for (int r = 0; r < 4; ++r) tmp[r] = f2bf(acc[m][n][r]);
      *(uint2*)(Cc + dv * 64 + m * 16 + rq) = *(uint2*)tmp;
    }
}

// ---------------- Phase B: chunk scan on bf16 S^T, f32 running state ----------------
__global__ __launch_bounds__(256) void chunk_scan_kernel(
    ushort* __restrict__ STbuf, const float* __restrict__ EGtot) {
  const int blk = blockIdx.x;      // 256 = bh*4 + qd
  const int bh = blk >> 2, qd = blk & 3;
  const int th = threadIdx.x;
  const int dv = qd * 32 + (th >> 3);
  const int k0 = (th & 7) * 8;
  ushort* base = STbuf + (long)bh * 32 * 8192 + dv * 64 + k0;
  const float* eg = EGtot + (long)bh * 32 * 64 + k0;
  float S[8];
#pragma unroll
  for (int i = 0; i < 8; ++i) S[i] = 0.f;
  uint4 cv = *(const uint4*)base;
  float4 e0 = *(const float4*)(eg);
  float4 e1 = *(const float4*)(eg + 4);
  for (int c = 0; c < 32; ++c) {
    ushort* cur = base;
    base += 8192; eg += 64;
    uint4 nv = cv; float4 n0 = e0, n1 = e1;
    if (c < 31) {
      nv = *(const uint4*)base;
      n0 = *(const float4*)(eg);
      n1 = *(const float4*)(eg + 4);
    }
    float cf[8];
    unpack8(cv, cf);
    float ee[8] = {e0.x, e0.y, e0.z, e0.w, e1.x, e1.y, e1.z, e1.w};
    ushort so[8];
#pragma unroll
    for (int i = 0; i < 8; ++i) {
      so[i] = f2bf(S[i]);               // S_in for chunk c
      S[i] = S[i] * ee[i] + cf[i];      // propagate
    }
    *(uint4*)cur = *(uint4*)so;
    cv = nv; e0 = n0; e1 = n1;
  }
}

// ---------------- Phase C: chunk output + fused RMSNorm*swish gate ----------------
__global__ __launch_bounds__(256) void chunk_output_kernel(
    const ushort* __restrict__ qkvg, const ushort* __restrict__ gbuf,
    const ushort* __restrict__ STbuf, const float* __restrict__ norm_w,
    ushort* __restrict__ oo) {
  const int blk = blockIdx.x;
  const int bh = blk >> 5, c = blk & 31;
  const int b = bh >> 4, h = bh & 15;
  const long row0 = (long)b * 2048 + c * 64;
  const int th = threadIdx.x;

  // LDS pool (71,936 B -> 2 blocks/CU). P aliases gc (dead after exp-apply).
  __shared__ __align__(16) char pool[71936];
  float  (*gc)[65]  = (float(*)[65])(pool);             // 16640 B
  ushort (*qg)[72]  = (ushort(*)[72])(pool + 16640);    //  9216 B
  ushort (*kg)[72]  = (ushort(*)[72])(pool + 25856);    //  9216 B
  ushort (*vT)[72]  = (ushort(*)[72])(pool + 35072);    // 18432 B
  ushort (*STs)[72] = (ushort(*)[72])(pool + 53504);    // 18432 B
  ushort (*P)[72]   = (ushort(*)[72])(pool);            // alias over gc

  {
    const int t = th >> 2;
    const int k0 = (th & 3) * 16;
    const ushort* gp = gbuf + (row0 + t) * 1024 + h * 64 + k0;
    uint4 a = *(const uint4*)gp;
    uint4 b4 = *(const uint4*)(gp + 8);
    float f[8];
    unpack8(a, f);
#pragma unroll
    for (int j = 0; j < 8; ++j) gc[t][k0 + j] = f[j];
    unpack8(b4, f);
#pragma unroll
    for (int j = 0; j < 8; ++j) gc[t][k0 + 8 + j] = f[j];

    const ushort* qp = qkvg + (row0 + t) * 6144 + h * 64 + k0;
    *(uint4*)(&qg[t][k0])     = *(const uint4*)qp;
    *(uint4*)(&qg[t][k0 + 8]) = *(const uint4*)(qp + 8);
    const ushort* kp = qp + 1024;
    *(uint4*)(&kg[t][k0])     = *(const uint4*)kp;
    *(uint4*)(&kg[t][k0 + 8]) = *(const uint4*)(kp + 8);
  }
  {  // v transpose
    const int s = th & 63, kq = th >> 6;
    const ushort* vp = qkvg + (row0 + s) * 6144 + 2048 + h * 128 + kq * 32;
#pragma unroll
    for (int u = 0; u < 4; ++u) {
      uint4 vv = *(const uint4*)(vp + u * 8);
      const ushort* pv = (const ushort*)&vv;
#pragma unroll
      for (int j = 0; j < 8; ++j) vT[kq * 32 + u * 8 + j][s] = pv[j];
    }
  }
  {  // S_in direct bf16 load [128dv][64k]
    const int row = th >> 1;
    const int col0 = (th & 1) * 32;
    const ushort* sp = STbuf + (long)blk * 8192 + row * 64 + col0;
#pragma unroll
    for (int u = 0; u < 4; ++u)
      *(uint4*)(&STs[row][col0 + u * 8]) = *(const uint4*)(sp + u * 8);
  }
  __syncthreads();
  if (th < 64) {  // cumsum
    float s = 0.f;
    for (int t = 0; t < 64; ++t) { s += gc[t][th]; gc[t][th] = s; }
  }
  __syncthreads();
  {  // apply exp: qg *= exp(gc)*scale ; kg *= exp(-gc)
    const int t = th & 63, kb = (th >> 6) * 16;
#pragma unroll
    for (int u = 0; u < 2; ++u) {
      uint4 qv = *(const uint4*)(&qg[t][kb + u * 8]);
      uint4 kv = *(const uint4*)(&kg[t][kb + u * 8]);
      float qf[8], kf[8];
      unpack8(qv, qf); unpack8(kv, kf);
      ushort qo[8], ko[8];
#pragma unroll
      for (int j = 0; j < 8; ++j) {
        float g = gc[t][kb + u * 8 + j];
        qo[j] = f2bf(qf[j] * __expf(g) * 0.125f);
        ko[j] = f2bf(kf[j] * __expf(-g));
      }
      *(uint4*)(&qg[t][kb + u * 8]) = *(uint4*)qo;
      *(uint4*)(&kg[t][kb + u * 8]) = *(uint4*)ko;
    }
  }
  __syncthreads();   // gc dead after this point; P may now use its space

  const int w = th >> 6, l = th & 63;
  const int lr = l & 15, kq8 = (l >> 4) * 8;
  const int rq = (l >> 4) * 4;

  f32x4 acc1[4];
#pragma unroll
  for (int n = 0; n < 4; ++n) acc1[n] = (f32x4){0.f, 0.f, 0.f, 0.f};
#pragma unroll
  for (int kk = 0; kk < 64; kk += 32) {
    bf16x8 af = *(const bf16x8*)(&qg[w * 16 + lr][kk + kq8]);
#pragma unroll
    for (int n = 0; n < 4; ++n) {
      bf16x8 bv = *(const bf16x8*)(&kg[n * 16 + lr][kk + kq8]);
      acc1[n] = __builtin_amdgcn_mfma_f32_16x16x32_bf16(af, bv, acc1[n], 0, 0, 0);
    }
  }
#pragma unroll
  for (int n = 0; n < 4; ++n) {
    int s = n * 16 + lr;
#pragma unroll
    for (int r = 0; r < 4; ++r) {
      int t = w * 16 + rq + r;
      P[t][s] = f2bf(s <= t ? acc1[n][r] : 0.f);
    }
  }
  __syncthreads();

  f32x4 acc2[8];
#pragma unroll
  for (int n = 0; n < 8; ++n) acc2[n] = (f32x4){0.f, 0.f, 0.f, 0.f};
#pragma unroll
  for (int ks = 0; ks < 64; ks += 32) {
    bf16x8 af = *(const bf16x8*)(&P[w * 16 + lr][ks + kq8]);
#pragma unroll
    for (int n = 0; n < 8; ++n) {
      bf16x8 bv = *(const bf16x8*)(&vT[n * 16 + lr][ks + kq8]);
      acc2[n] = __builtin_amdgcn_mfma_f32_16x16x32_bf16(af, bv, acc2[n], 0, 0, 0);
    }
  }
#pragma unroll
  for (int kk = 0; kk < 64; kk += 32) {
    bf16x8 af = *(const bf16x8*)(&qg[w * 16 + lr][kk + kq8]);
#pragma unroll
    for (int n = 0; n < 8; ++n) {
      bf16x8 bv = *(const bf16x8*)(&STs[n * 16 + lr][kk + kq8]);
      acc2[n] = __builtin_amdgcn_mfma_f32_16x16x32_bf16(af, bv, acc2[n], 0, 0, 0);
    }
  }

  // gate values from global (coalesced-ish 32B groups), overlap with reduce
  float gv[8][4];
#pragma unroll
  for (int n = 0; n < 8; ++n) {
    int dv = n * 16 + lr;
#pragma unroll
    for (int r = 0; r < 4; ++r)
      gv[n][r] = bf2f(qkvg[(row0 + w * 16 + rq + r) * 6144 + 4096 + h * 128 + dv]);
  }

  float sumsq[4] = {0.f, 0.f, 0.f, 0.f};
#pragma unroll
  for (int n = 0; n < 8; ++n)
#pragma unroll
    for (int r = 0; r < 4; ++r) sumsq[r] += acc2[n][r] * acc2[n][r];
#pragma unroll
  for (int d = 1; d < 16; d <<= 1)
#pragma unroll
    for (int r = 0; r < 4; ++r) sumsq[r] += __shfl_xor(sumsq[r], d);
  float inv[4];
#pragma unroll
  for (int r = 0; r < 4; ++r) inv[r] = rsqrtf(sumsq[r] * (1.f / 128.f) + 1e-5f);

#pragma unroll
  for (int n = 0; n < 8; ++n) {
    int dv = n * 16 + lr;
    float nw = norm_w[dv];
#pragma unroll
    for (int r = 0; r < 4; ++r) {
      float g = gv[n][r];
      float sw = g / (1.f + __expf(-g));
      oo[(row0 + w * 16 + rq + r) * 2048 + h * 128 + dv] =
          f2bf(acc2[n][r] * inv[r] * nw * sw);
    }
  }
}

extern "C" void kernel_launch(void* const* d_in, const int* in_sizes, int n_in,
                              void* d_out, int out_size, void* d_ws, size_t ws_size,
                              hipStream_t stream) {
  const float* x      = (const float*)d_in[0];
  const float* Wq     = (const float*)d_in[1];
  const float* Wk     = (const float*)d_in[2];
  const float* Wv     = (const float*)d_in[3];
  const float* Wg     = (const float*)d_in[4];
  const float* Wgk1   = (const float*)d_in[5];
  const float* Wgk2   = (const float*)d_in[6];
  const float* bgk2   = (const float*)d_in[7];
  const float* norm_w = (const float*)d_in[8];
  const float* Wo     = (const float*)d_in[9];
  float* out = (float*)d_out;

  char* ws = (char*)d_ws;
  ushort* WT    = (ushort*)(ws);                       // [6144][2048] bf16  25,165,824
  ushort* WoT   = (ushort*)(ws + 25165824);            // [2048][2048] bf16   8,388,608
  ushort* qkvg  = (ushort*)(ws + 33554432);            // [8192][6144] bf16 100,663,296
  ushort* gbuf  = (ushort*)(ws + 134217728);           // [8192][1024] bf16  16,777,216
  ushort* STbuf = (ushort*)(ws + 150994944);           // [2048][128][64] bf16 33,554,432
  ushort* xb    = (ushort*)(ws + 150994944);           // overlay: dead after gate_kernel
  float*  EGtot = (float*)(ws + 184549376);            // [2048][64] f32        524,288
  ushort* oo    = (ushort*)(ws + 185073664);           // [8192][2048] bf16  33,554,432
  // end: 218,628,096 < 256 MiB

  dim3 blk(256);
  f32_to_bf16<<<dim3(8192), blk, 0, stream>>>(x, xb, (long)8192 * 2048);
  transpose_f32_bf16<<<dim3(16, 32), blk, 0, stream>>>(Wq, WT, 2048, 1024);
  transpose_f32_bf16<<<dim3(16, 32), blk, 0, stream>>>(Wk, WT + (size_t)1024 * 2048, 2048, 1024);
  transpose_f32_bf16<<<dim3(32, 32), blk, 0, stream>>>(Wv, WT + (size_t)2048 * 2048, 2048, 2048);
  transpose_f32_bf16<<<dim3(32, 32), blk, 0, stream>>>(Wg, WT + (size_t)4096 * 2048, 2048, 2048);
  transpose_f32_bf16<<<dim3(32, 32), blk, 0, stream>>>(Wo, WoT, 2048, 2048);

  gemm_bt8<ushort><<<dim3(768), dim3(512), 0, stream>>>(xb, WT, qkvg, 8192, 6144, 2048);
  gate_kernel<<<dim3(8192), blk, 0, stream>>>(xb, Wgk1, Wgk2, bgk2, gbuf);

  chunk_contrib_kernel<<<dim3(2048), blk, 0, stream>>>(qkvg, gbuf, STbuf, EGtot);
  chunk_scan_kernel<<<dim3(256), blk, 0, stream>>>(STbuf, EGtot);
  chunk_output_kernel<<<dim3(2048), blk, 0, stream>>>(qkvg, gbuf, STbuf, norm_w, oo);

  gemm_bt8<float><<<dim3(256), dim3(512), 0, stream>>>(oo, WoT, out, 8192, 2048, 2048);
}